// Round 6
// baseline (399.463 us; speedup 1.0000x reference)
//
#include <hip/hip_runtime.h>
#include <cstddef>
#include <cstdint>

#define THRESH 0.8f
#define DECAY  0.2f

typedef unsigned short ushort_t;
typedef __attribute__((ext_vector_type(8))) short bf16x8;
typedef __attribute__((ext_vector_type(4))) float f32x4;
typedef __attribute__((ext_vector_type(4))) int i32x4;   // also 16 x i8 operand

__device__ __forceinline__ ushort_t f2bf(float f) {
    union { float f; unsigned u; } v; v.f = f;
    unsigned r = v.u + 0x7FFFu + ((v.u >> 16) & 1u);
    return (ushort_t)(r >> 16);
}
__device__ __forceinline__ float bf2f(ushort_t h) {
    union { unsigned u; float f; } v; v.u = ((unsigned)h) << 16;
    return v.f;
}
__device__ __forceinline__ float blo(unsigned u) {
    union { unsigned x; float f; } v; v.x = u << 16; return v.f;
}
__device__ __forceinline__ float bhi(unsigned u) {
    union { unsigned x; float f; } v; v.x = u & 0xFFFF0000u; return v.f;
}

// async global->LDS, 16B per lane; LDS dest = wave-uniform base + lane*16
__device__ __forceinline__ void gload16(const void* g, void* l) {
    __builtin_amdgcn_global_load_lds(
        (const __attribute__((address_space(1))) void*)g,
        (__attribute__((address_space(3))) void*)l,
        16, 0, 0);
}

// compiler-invisible LDS read (keeps waitcnt control out of the compiler)
#define DSREAD(dst, addr, off) \
    asm volatile("ds_read_b128 %0, %1 offset:" #off : "=v"(dst) : "v"(addr))

#define MM(i, j, a, w) \
    acc[i][j] = __builtin_amdgcn_mfma_f32_16x16x32_bf16(a, w, acc[i][j], 0, 0, 0)

// concat-K tile -> physical ushort offset (dedup: A phys = [hi|lo] K=1024,
// logical K=1536 = [hi|hi|lo]; W phys = [wh|wl], logical [wh|wl|wh])
__device__ __forceinline__ constexpr int atile(int t) {
    return t < 16 ? t * 32 : (t < 32 ? (t - 16) * 32 : 512 + (t - 32) * 32);
}
__device__ __forceinline__ constexpr int wtile(int t) {
    return t < 16 ? t * 32 : (t < 32 ? 512 + (t - 16) * 32 : (t - 32) * 32);
}

// ---------------------------------------------------------------------------
// Fused currents-GEMM + LIF recurrence.  R5 structure, plus:
//  - dedup'd operands (A 10240x1024, W 3072x1024; compile-time tile remap
//    in the fully-unrolled K-loop -> same accumulation order, less HBM)
//  - XCD-aware grid swizzle: xcd=bid&7 owns by in {2*xcd, 2*xcd+1} x all bx
//    -> W panels (1.2 MB) L2-resident per XCD instead of 8x re-fetch
//  - counted lgkmcnt interleave: af0+wf0..2 first, lgkmcnt(4) -> row-0
//    MFMAs overlap the remaining 4 ds_read returns
// Pipeline otherwise identical to R5 (3 bufs, dist-2 prefetch, per-wave
// counted vmcnt, 2 barriers/tile, setprio).
// ---------------------------------------------------------------------------
__global__ __launch_bounds__(512, 4) void fused_cur_lif(
    const ushort_t* __restrict__ A, const ushort_t* __restrict__ W,
    const float* __restrict__ b123, const float* __restrict__ wl,
    const float* __restrict__ bl, signed char* __restrict__ xb)
{
    // [buf][ A: 160x32 (5120 us) | B: 192x32 (6144 us) ] = 22.5KB x 3
    __shared__ ushort_t lds[3][11264];

    const int t = threadIdx.x;
    const int bid = blockIdx.x;          // 0..1023
    const int xcd = bid & 7;
    const int idx = bid >> 3;            // 0..127
    const int by = xcd * 2 + (idx >> 6); // 0..15
    const int bx = idx & 63;             // 0..63
    const int lane = t & 63;
    const int wv = t >> 6;
    const int wm = (wv >> 2) * 80;       // wave m-offset: 0 / 80
    const int wn = (wv & 3) * 48;        // wave n-offset: 0/48/96/144
    const int fr = lane & 15;
    const int fq = lane >> 4;
    const int swz16 = (fq ^ ((fr >> 1) & 3)) * 16;   // read swizzle, bytes

    // per-buffer ds_read base addresses (bytes); buffer stride 22528
    const unsigned av0 = (unsigned)((wm + fr) * 64 + swz16);
    const unsigned av1 = av0 + 22528;
    const unsigned av2 = av0 + 45056;
    const unsigned bv0 = (unsigned)(10240 + (wn + fr) * 64 + swz16);
    const unsigned bv1 = bv0 + 22528;
    const unsigned bv2 = bv0 + 45056;

    // staging role: waves 0-4 stage A (2 x 16-row groups), 5-7 stage B (4)
    const ushort_t* src0; const ushort_t* src1;
    const ushort_t* src2; const ushort_t* src3;
    int dst0, dst1, dst2, dst3;
    if (wv < 5) {
        const int rl0 = wv * 32 + (lane >> 2);
        const int rl1 = rl0 + 16;
        src0 = A + (size_t)(bx * 160 + rl0) * 1024 + ((lane & 3) ^ ((rl0 >> 1) & 3)) * 8;
        src1 = A + (size_t)(bx * 160 + rl1) * 1024 + ((lane & 3) ^ ((rl1 >> 1) & 3)) * 8;
        src2 = src0; src3 = src1;
        dst0 = rl0 * 32 + (lane & 3) * 8;
        dst1 = rl1 * 32 + (lane & 3) * 8;
        dst2 = dst0; dst3 = dst1;
    } else {
        const int rb = (wv - 5) * 64 + (lane >> 2);
        src0 = W + (size_t)(by * 192 + rb) * 1024 + ((lane & 3) ^ ((rb >> 1) & 3)) * 8;
        src1 = src0 + (size_t)16 * 1024;
        src2 = src0 + (size_t)32 * 1024;
        src3 = src0 + (size_t)48 * 1024;
        dst0 = 5120 + rb * 32 + (lane & 3) * 8;
        dst1 = dst0 + 16 * 32;
        dst2 = dst0 + 32 * 32;
        dst3 = dst0 + 48 * 32;
    }

#define STAGE(tile, sbuf)                                              \
    do {                                                               \
        ushort_t* lb_ = &lds[sbuf][0];                                 \
        if (wv < 5) {                                                  \
            gload16(src0 + atile(tile), lb_ + dst0);                   \
            gload16(src1 + atile(tile), lb_ + dst1);                   \
        } else {                                                       \
            gload16(src0 + wtile(tile), lb_ + dst0);                   \
            gload16(src1 + wtile(tile), lb_ + dst1);                   \
            gload16(src2 + wtile(tile), lb_ + dst2);                   \
            gload16(src3 + wtile(tile), lb_ + dst3);                   \
        }                                                              \
    } while (0)

#define COMPUTE(av_, bv_)                                              \
    do {                                                               \
        bf16x8 af0, af1, af2, af3, af4, wf0, wf1, wf2;                 \
        DSREAD(af0, av_, 0);                                           \
        DSREAD(wf0, bv_, 0);                                           \
        DSREAD(wf1, bv_, 1024);                                        \
        DSREAD(wf2, bv_, 2048);                                        \
        DSREAD(af1, av_, 1024);                                        \
        DSREAD(af2, av_, 2048);                                        \
        DSREAD(af3, av_, 3072);                                        \
        DSREAD(af4, av_, 4096);                                        \
        asm volatile("s_waitcnt lgkmcnt(4)" ::: "memory");             \
        __builtin_amdgcn_sched_barrier(0);                             \
        __builtin_amdgcn_s_setprio(1);                                 \
        MM(0, 0, af0, wf0); MM(0, 1, af0, wf1); MM(0, 2, af0, wf2);    \
        asm volatile("s_waitcnt lgkmcnt(0)" ::: "memory");             \
        __builtin_amdgcn_sched_barrier(0);                             \
        MM(1, 0, af1, wf0); MM(1, 1, af1, wf1); MM(1, 2, af1, wf2);    \
        MM(2, 0, af2, wf0); MM(2, 1, af2, wf1); MM(2, 2, af2, wf2);    \
        MM(3, 0, af3, wf0); MM(3, 1, af3, wf1); MM(3, 2, af3, wf2);    \
        MM(4, 0, af4, wf0); MM(4, 1, af4, wf1); MM(4, 2, af4, wf2);    \
        __builtin_amdgcn_s_setprio(0);                                 \
    } while (0)

    f32x4 acc[5][3];
#pragma unroll
    for (int i = 0; i < 5; i++)
#pragma unroll
        for (int j = 0; j < 3; j++) {
            f32x4 z = {0.f, 0.f, 0.f, 0.f};
            acc[i][j] = z;
        }

    // prologue: tiles 0,1 in flight
    STAGE(0, 0);
    STAGE(1, 1);

    // main loop, fully unrolled: tiles 0..45, staging 2..47
#pragma unroll
    for (int tt = 0; tt < 46; ++tt) {
        STAGE(tt + 2, (tt + 2) % 3);
        if (wv < 5) asm volatile("s_waitcnt vmcnt(4)" ::: "memory");
        else        asm volatile("s_waitcnt vmcnt(8)" ::: "memory");
        __builtin_amdgcn_s_barrier();
        __builtin_amdgcn_sched_barrier(0);
        const unsigned av_ = (tt % 3 == 0) ? av0 : (tt % 3 == 1) ? av1 : av2;
        const unsigned bv_ = (tt % 3 == 0) ? bv0 : (tt % 3 == 1) ? bv1 : bv2;
        COMPUTE(av_, bv_);
        __builtin_amdgcn_s_barrier();
        __builtin_amdgcn_sched_barrier(0);
    }
    // tt = 46 (buffer 1): only tile 47's loads still outstanding
    if (wv < 5) asm volatile("s_waitcnt vmcnt(2)" ::: "memory");
    else        asm volatile("s_waitcnt vmcnt(4)" ::: "memory");
    __builtin_amdgcn_s_barrier();
    __builtin_amdgcn_sched_barrier(0);
    COMPUTE(av1, bv1);
    __builtin_amdgcn_s_barrier();
    __builtin_amdgcn_sched_barrier(0);
    // tt = 47 (buffer 2): drain
    asm volatile("s_waitcnt vmcnt(0)" ::: "memory");
    __builtin_amdgcn_s_barrier();
    __builtin_amdgcn_sched_barrier(0);
    COMPUTE(av2, bv2);
#undef STAGE
#undef COMPUTE

    // ---- epilogue: in-register LIF recurrence (replaces recur_kernel) ----
    const int ch = by * 64 + (wv & 3) * 16 + fr;
    const float b1c = b123[ch];
    const float b2c = b123[1024 + ch];
    const float b3c = b123[2048 + ch];
    const float wl0 = wl[0], wl1 = wl[1], wl2 = wl[2], bl0 = bl[0];
    const int bbase = bx * 32 + (wv >> 2) * 16 + fq * 4;
#pragma unroll
    for (int r = 0; r < 4; r++) {
        float m0 = 0.f, m1 = 0.f, m2 = 0.f, m3 = 0.f;
        int s0 = 0, s1 = 0, s2 = 0, s3 = 0;
#pragma unroll
        for (int f = 0; f < 5; f++) {
            const float i1 = acc[f][0][r] + b1c;
            const float i2 = acc[f][1][r] + b2c;
            const float i3 = acc[f][2][r] + b3c;
#pragma unroll
            for (int rep = 0; rep < 3; rep++) {
                const float inner = m0 * wl0 + m1 * wl1 + m2 * wl2 + bl0;
                const float n0 = i1 + ((m0 > THRESH) ? 0.f : DECAY * m0);
                const float n1 = i2 + ((m1 > THRESH) ? 0.f : DECAY * m1);
                const float n2 = i3 + ((m2 > THRESH) ? 0.f : DECAY * m2);
                const float n3 = inner + ((m3 > THRESH) ? 0.f : DECAY * m3);
                m0 = n0; m1 = n1; m2 = n2; m3 = n3;
                s0 += (n0 > THRESH); s1 += (n1 > THRESH);
                s2 += (n2 > THRESH); s3 += (n3 > THRESH);
            }
        }
        uchar4 o;
        o.x = (unsigned char)s0; o.y = (unsigned char)s1;
        o.z = (unsigned char)s2; o.w = (unsigned char)s3;
        *(uchar4*)&xb[(size_t)(bbase + r) * 4096 + ch * 4] = o;
    }
}

// ---------------------------------------------------------------------------
// MLP layer 1, int8 MFMA at FULL rate (16x16x64, 16B frags).
// ---------------------------------------------------------------------------
__global__ __launch_bounds__(256) void mlp1_i8(
    const signed char* __restrict__ A, const signed char* __restrict__ W,
    const float* __restrict__ wsc, const float* __restrict__ bias,
    ushort_t* __restrict__ C)
{
    __shared__ signed char sA[64 * 64];    // 4 KB
    __shared__ signed char sW[128 * 64];   // 8 KB

    const int t = threadIdx.x;
    const int mBase = blockIdx.x * 64;
    const int nBase = blockIdx.y * 128;

    const int lane = t & 63;
    const int wv = t >> 6;
    const int wn = wv * 32;
    const int fr = lane & 15;
    const int fq = lane >> 4;            // k-offset = fq*16 bytes
    const int fsw = (fq ^ ((fr >> 1) & 3)) * 16;  // swizzled read chunk (bytes)

    const int r0 = t >> 2;                           // staging row 0..63
    const int cc = ((t & 3) ^ ((t >> 3) & 3)) * 16;  // pre-swizzled src byte-col

    i32x4 acc[4][2];
#pragma unroll
    for (int i = 0; i < 4; i++)
#pragma unroll
        for (int j = 0; j < 2; j++) {
            i32x4 z = {0, 0, 0, 0};
            acc[i][j] = z;
        }

    for (int k0 = 0; k0 < 4096; k0 += 64) {
        gload16(&A[(size_t)(mBase + r0) * 4096 + k0 + cc], &sA[t * 16]);
        gload16(&W[(size_t)(nBase + r0) * 4096 + k0 + cc], &sW[t * 16]);
        gload16(&W[(size_t)(nBase + 64 + r0) * 4096 + k0 + cc], &sW[4096 + t * 16]);
        __syncthreads();

        i32x4 af[4], wf[2];
#pragma unroll
        for (int i = 0; i < 4; i++)
            af[i] = *(const i32x4*)&sA[(i * 16 + fr) * 64 + fsw];
#pragma unroll
        for (int j = 0; j < 2; j++)
            wf[j] = *(const i32x4*)&sW[(wn + j * 16 + fr) * 64 + fsw];
#pragma unroll
        for (int i = 0; i < 4; i++)
#pragma unroll
            for (int j = 0; j < 2; j++)
                acc[i][j] = __builtin_amdgcn_mfma_i32_16x16x64_i8(af[i], wf[j], acc[i][j], 0, 0, 0);
        __syncthreads();
    }

#pragma unroll
    for (int j = 0; j < 2; j++) {
        const int col = nBase + wn + j * 16 + fr;
        const float sc = wsc[col];
        const float bv = bias[col];
#pragma unroll
        for (int i = 0; i < 4; i++)
#pragma unroll
            for (int r = 0; r < 4; r++) {
                const int row = mBase + i * 16 + fq * 4 + r;
                const float v = (float)acc[i][j][r] * sc + bv;
                C[(size_t)row * 2048 + col] = f2bf(fmaxf(v, 0.f));
            }
    }
}

// ---------------------------------------------------------------------------
// MLP layer 2: bf16, 64x128 tile, block-diagonal.
// ---------------------------------------------------------------------------
__global__ __launch_bounds__(256) void mlp2_bf16(
    const ushort_t* __restrict__ A, const ushort_t* __restrict__ W,
    const float* __restrict__ bias, ushort_t* __restrict__ C,
    int N, int K, int lda, int ldw, int ldc, int aHalfOff)
{
    __shared__ ushort_t sA[64 * 32];
    __shared__ ushort_t sW[128 * 32];

    const int t = threadIdx.x;
    const int mBase = blockIdx.x * 64;
    const int nBase = blockIdx.y * 128;
    const int aOff = (2 * nBase >= N) ? aHalfOff : 0;

    const int lane = t & 63;
    const int wv = t >> 6;
    const int wn = wv * 32;
    const int fr = lane & 15;
    const int fq = lane >> 4;
    const int fsw = (fq ^ ((fr >> 1) & 3)) * 8;   // swizzled read chunk (ushorts)

    const int r0 = t >> 2;                           // 0..63
    const int cc = ((t & 3) ^ ((t >> 3) & 3)) * 8;   // pre-swizzled src k-col

    f32x4 acc[4][2];
#pragma unroll
    for (int i = 0; i < 4; i++)
#pragma unroll
        for (int j = 0; j < 2; j++) {
            f32x4 z = {0.f, 0.f, 0.f, 0.f};
            acc[i][j] = z;
        }

    for (int k0 = 0; k0 < K; k0 += 32) {
        gload16(&A[(size_t)(mBase + r0) * lda + aOff + k0 + cc], &sA[t * 8]);
        gload16(&W[(size_t)(nBase + r0) * ldw + k0 + cc], &sW[t * 8]);
        gload16(&W[(size_t)(nBase + 64 + r0) * ldw + k0 + cc], &sW[2048 + t * 8]);
        __syncthreads();

        bf16x8 af[4], wf[2];
#pragma unroll
        for (int i = 0; i < 4; i++)
            af[i] = *(const bf16x8*)&sA[(i * 16 + fr) * 32 + fsw];
#pragma unroll
        for (int j = 0; j < 2; j++)
            wf[j] = *(const bf16x8*)&sW[(wn + j * 16 + fr) * 32 + fsw];
#pragma unroll
        for (int i = 0; i < 4; i++)
#pragma unroll
            for (int j = 0; j < 2; j++)
                acc[i][j] = __builtin_amdgcn_mfma_f32_16x16x32_bf16(af[i], wf[j], acc[i][j], 0, 0, 0);
        __syncthreads();
    }

#pragma unroll
    for (int j = 0; j < 2; j++) {
        const int col = nBase + wn + j * 16 + fr;
        const float bv = bias[col];
#pragma unroll
        for (int i = 0; i < 4; i++)
#pragma unroll
            for (int r = 0; r < 4; r++) {
                const int row = mBase + i * 16 + fq * 4 + r;
                C[(size_t)row * ldc + col] = f2bf(fmaxf(acc[i][j][r] + bv, 0.f));
            }
    }
}

// ---------------------------------------------------------------------------
// Consolidated prep:
//  - state -> A'' (row-permuted, phys K=1024 [hi|lo])
//  - w1/w2/w3 -> W'' (row-permuted, phys K=1024 [wh|wl])
//  - w11|w21 -> int8 rows with per-row scale (shuffle-based reduction)
//  - w12/w22 -> bf16; bias packing
// ---------------------------------------------------------------------------
__device__ __forceinline__ void split_state_perm(const float4* src, ushort4* dst,
                                                 int base, int t) {
#pragma unroll
    for (int p = 0; p < 4; p++) {
        const int i = base * 1024 + p * 256 + t;
        const float4 v = src[i];
        ushort4 h, l;
        h.x = f2bf(v.x); l.x = f2bf(v.x - bf2f(h.x));
        h.y = f2bf(v.y); l.y = f2bf(v.y - bf2f(h.y));
        h.z = f2bf(v.z); l.z = f2bf(v.z - bf2f(h.z));
        h.w = f2bf(v.w); l.w = f2bf(v.w - bf2f(h.w));
        const int s = i >> 7, c4 = i & 127;      // source row (b*5+f), f4-col
        const int b = s / 5, f = s - b * 5;
        const int m = ((b >> 5) * 160) + (((b >> 4) & 1) * 80) + (f << 4) + (b & 15);
        ushort4* row = dst + (size_t)m * 256;    // 1024 ushorts = 256 ushort4
        row[c4] = h; row[128 + c4] = l;          // [hi | lo]
    }
}
__device__ __forceinline__ void split_w_perm(const float4* src, ushort4* dst,
                                             int base, int t, int j) {
#pragma unroll
    for (int p = 0; p < 4; p++) {
        const int i = base * 1024 + p * 256 + t;
        const float4 v = src[i];
        ushort4 h, l;
        h.x = f2bf(v.x); l.x = f2bf(v.x - bf2f(h.x));
        h.y = f2bf(v.y); l.y = f2bf(v.y - bf2f(h.y));
        h.z = f2bf(v.z); l.z = f2bf(v.z - bf2f(h.z));
        h.w = f2bf(v.w); l.w = f2bf(v.w - bf2f(h.w));
        const int c = i >> 7, c4 = i & 127;      // source row (channel), f4-col
        const int n = ((c >> 6) * 192) + (((c >> 4) & 3) * 48) + (j << 4) + (c & 15);
        ushort4* row = dst + (size_t)n * 256;
        row[c4] = h; row[128 + c4] = l;          // [wh | wl]
    }
}
__device__ __forceinline__ void do_cvt4(const float4* src, ushort4* dst,
                                        int base, int t) {
#pragma unroll
    for (int p = 0; p < 4; p++) {
        const int i = base * 1024 + p * 256 + t;
        const float4 v = src[i];
        ushort4 h;
        h.x = f2bf(v.x); h.y = f2bf(v.y); h.z = f2bf(v.z); h.w = f2bf(v.w);
        dst[i] = h;
    }
}
__device__ __forceinline__ int q8(float x, float inv) {
    int q = (int)rintf(x * inv);
    q = q > 127 ? 127 : (q < -127 ? -127 : q);
    return q & 0xff;
}

__global__ __launch_bounds__(256) void prep_kernel(
    const float* __restrict__ state,
    const float* __restrict__ w1, const float* __restrict__ w2,
    const float* __restrict__ w3,
    const float* __restrict__ w11, const float* __restrict__ w21,
    const float* __restrict__ w12, const float* __restrict__ w22,
    const float* __restrict__ b1, const float* __restrict__ b2,
    const float* __restrict__ b3, const float* __restrict__ b11,
    const float* __restrict__ b21, const float* __restrict__ b12,
    const float* __restrict__ b22,
    ushort_t* __restrict__ Ap, ushort_t* __restrict__ Wp,
    signed char* __restrict__ w1q, float* __restrict__ wsc,
    ushort_t* __restrict__ w2b,
    float* __restrict__ b123, float* __restrict__ bb1, float* __restrict__ bb2)
{
    const int bid = blockIdx.x;
    const int t = threadIdx.x;
    if (bid < 1280) {
        split_state_perm((const float4*)state, (ushort4*)Ap, bid, t);
    } else if (bid < 1408) {
        split_w_perm((const float4*)w1, (ushort4*)Wp, bid - 1280, t, 0);
    } else if (bid < 1536) {
        split_w_perm((const float4*)w2, (ushort4*)Wp, bid - 1408, t, 1);
    } else if (bid < 1664) {
        split_w_perm((const float4*)w3, (ushort4*)Wp, bid - 1536, t, 2);
    } else if (bid < 3712) {
        // one block per output row of [w11 ; w21] -> int8 + per-row scale
        const int r = bid - 1664;
        const float* src = (r < 1024) ? (w11 + (size_t)r * 4096)
                                      : (w21 + (size_t)(r - 1024) * 4096);
        __shared__ float red4[4];
        float4 v[4];
        float lmax = 0.f;
#pragma unroll
        for (int p = 0; p < 4; p++) {
            v[p] = ((const float4*)src)[t * 4 + p];
            lmax = fmaxf(lmax, fmaxf(fmaxf(fabsf(v[p].x), fabsf(v[p].y)),
                                     fmaxf(fabsf(v[p].z), fabsf(v[p].w))));
        }
#pragma unroll
        for (int d = 1; d < 64; d <<= 1)
            lmax = fmaxf(lmax, __shfl_xor(lmax, d, 64));
        if ((t & 63) == 0) red4[t >> 6] = lmax;
        __syncthreads();
        const float gmax = fmaxf(fmaxf(fmaxf(red4[0], red4[1]),
                                       fmaxf(red4[2], red4[3])), 1e-30f);
        const float inv = 127.0f / gmax;
        int4 o;
        o.x = q8(v[0].x, inv) | (q8(v[0].y, inv) << 8) | (q8(v[0].z, inv) << 16) | (q8(v[0].w, inv) << 24);
        o.y = q8(v[1].x, inv) | (q8(v[1].y, inv) << 8) | (q8(v[1].z, inv) << 16) | (q8(v[1].w, inv) << 24);
        o.z = q8(v[2].x, inv) | (q8(v[2].y, inv) << 8) | (q8(v[2].z, inv) << 16) | (q8(v[2].w, inv) << 24);
        o.w = q8(v[3].x, inv) | (q8(v[3].y, inv) << 8) | (q8(v[3].z, inv) << 16) | (q8(v[3].w, inv) << 24);
        ((int4*)(w1q + (size_t)r * 4096))[t] = o;
        if (t == 0) wsc[r] = gmax / (127.0f * 15.0f);
    } else if (bid < 3968) {
        do_cvt4((const float4*)w12, (ushort4*)w2b, bid - 3712, t);
    } else if (bid < 4224) {
        do_cvt4((const float4*)w22, (ushort4*)(w2b + 1048576), bid - 3968, t);
    } else {
#pragma unroll
        for (int p = 0; p < 4; p++) {
            const int i = p * 256 + t;
            b123[i] = b1[i]; b123[1024 + i] = b2[i]; b123[2048 + i] = b3[i];
            bb1[i] = b11[i]; bb1[1024 + i] = b21[i];
            bb2[i] = b12[i]; bb2[1024 + i] = b22[i];
        }
    }
}

// ---------------------------------------------------------------------------
// Heads (both branches): out[b][n] = (clip?)(h2[b][off+k] . w[n][k] + bias[n])
// ---------------------------------------------------------------------------
__global__ __launch_bounds__(256) void head_kernel(
    const ushort_t* __restrict__ h, const float* __restrict__ wm,
    const float* __restrict__ bm, const float* __restrict__ ws,
    const float* __restrict__ bs, float* __restrict__ out)
{
    const int t = threadIdx.x;
    const int branch = blockIdx.x >> 8;
    const int n = t & 31;
    const int b = (blockIdx.x & 255) * 8 + (t >> 5);
    const ushort_t* hr = h + (size_t)b * 2048 + branch * 1024;
    const float* wr = (branch ? ws : wm) + (size_t)n * 1024;
    float s = 0.f;
#pragma unroll 4
    for (int k = 0; k < 1024; k += 8) {
        const uint4 hv = *(const uint4*)&hr[k];
        const float4 w0 = *(const float4*)&wr[k];
        const float4 w1 = *(const float4*)&wr[k + 4];
        s += blo(hv.x) * w0.x + bhi(hv.x) * w0.y
           + blo(hv.y) * w0.z + bhi(hv.y) * w0.w
           + blo(hv.z) * w1.x + bhi(hv.z) * w1.y
           + blo(hv.w) * w1.z + bhi(hv.w) * w1.w;
    }
    s += (branch ? bs : bm)[n];
    if (branch) s = fminf(fmaxf(s, -20.f), 2.f);
    out[(size_t)branch * 65536 + (size_t)b * 32 + n] = s;
}

// ---------------------------------------------------------------------------
extern "C" void kernel_launch(void* const* d_in, const int* in_sizes, int n_in,
                              void* d_out, int out_size, void* d_ws, size_t ws_size,
                              hipStream_t stream)
{
    const float* state = (const float*)d_in[0];
    const float* w1  = (const float*)d_in[1];  const float* b1  = (const float*)d_in[2];
    const float* w2  = (const float*)d_in[3];  const float* b2  = (const float*)d_in[4];
    const float* w3  = (const float*)d_in[5];  const float* b3  = (const float*)d_in[6];
    const float* wl  = (const float*)d_in[7];  const float* bl  = (const float*)d_in[8];
    const float* w11 = (const float*)d_in[9];  const float* b11 = (const float*)d_in[10];
    const float* w12 = (const float*)d_in[11]; const float* b12 = (const float*)d_in[12];
    const float* w21 = (const float*)d_in[13]; const float* b21 = (const float*)d_in[14];
    const float* w22 = (const float*)d_in[15]; const float* b22 = (const float*)d_in[16];
    const float* wm  = (const float*)d_in[17]; const float* bm  = (const float*)d_in[18];
    const float* ws  = (const float*)d_in[19]; const float* bs  = (const float*)d_in[20];
    float* out = (float*)d_out;

    // ---- workspace layout ----
    char* wp = (char*)d_ws;
    ushort_t*    Ap    = (ushort_t*)wp;    wp += (size_t)10240 * 1024 * 2;   // 21MB
    ushort_t*    Wp    = (ushort_t*)wp;    wp += (size_t)3072 * 1024 * 2;    // 6.3MB
    signed char* xb    = (signed char*)wp; wp += (size_t)2048 * 4096;        // int8 counts
    signed char* w1q   = (signed char*)wp; wp += (size_t)2048 * 4096;        // int8 [w11;w21]
    ushort_t*    w2b   = (ushort_t*)wp;    wp += (size_t)2048 * 1024 * 2;
    ushort_t*    h1    = (ushort_t*)wp;    wp += (size_t)2048 * 2048 * 2;
    ushort_t*    h2    = (ushort_t*)wp;    wp += (size_t)2048 * 2048 * 2;
    float*       wsc   = (float*)wp;       wp += 2048 * 4;
    float*       b123  = (float*)wp;       wp += 3072 * 4;
    float*       bb1   = (float*)wp;       wp += 2048 * 4;
    float*       bb2   = (float*)wp;       wp += 2048 * 4;

    // ---- prep: permuted splits (dedup'd), int8 quant, cvts, bias packing ----
    prep_kernel<<<4225, 256, 0, stream>>>(
        state, w1, w2, w3, w11, w21, w12, w22,
        b1, b2, b3, b11, b21, b12, b22,
        Ap, Wp, w1q, wsc, w2b, b123, bb1, bb2);

    // ---- fused currents GEMM + LIF -> spike counts int8 [2048, 4096] ----
    fused_cur_lif<<<1024, 512, 0, stream>>>(Ap, Wp, b123, wl, bl, xb);

    // ---- MLP layer 1 (both branches) i8 K=64 MFMA, 512 blocks ----
    mlp1_i8<<<dim3(32, 16), 256, 0, stream>>>(xb, w1q, wsc, bb1, h1);

    // ---- MLP layer 2 (block-diagonal) bf16, 512 blocks ----
    mlp2_bf16<<<dim3(32, 16), 256, 0, stream>>>(
        h1, w2b, bb2, h2, 2048, 1024, 2048, 1024, 2048, 1024);

    // ---- heads (both branches) ----
    head_kernel<<<512, 256, 0, stream>>>(h2, wm, bm, ws, bs, out);
}

// Round 7
// 386.114 us; speedup vs baseline: 1.0346x; 1.0346x over previous
//
#include <hip/hip_runtime.h>
#include <cstddef>
#include <cstdint>

#define THRESH 0.8f
#define DECAY  0.2f

typedef unsigned short ushort_t;
typedef __attribute__((ext_vector_type(8))) short bf16x8;
typedef __attribute__((ext_vector_type(4))) float f32x4;
typedef __attribute__((ext_vector_type(4))) int i32x4;   // also 16 x i8 operand

__device__ __forceinline__ ushort_t f2bf(float f) {
    union { float f; unsigned u; } v; v.f = f;
    unsigned r = v.u + 0x7FFFu + ((v.u >> 16) & 1u);
    return (ushort_t)(r >> 16);
}
__device__ __forceinline__ float bf2f(ushort_t h) {
    union { unsigned u; float f; } v; v.u = ((unsigned)h) << 16;
    return v.f;
}
__device__ __forceinline__ float blo(unsigned u) {
    union { unsigned x; float f; } v; v.x = u << 16; return v.f;
}
__device__ __forceinline__ float bhi(unsigned u) {
    union { unsigned x; float f; } v; v.x = u & 0xFFFF0000u; return v.f;
}

// async global->LDS, 16B per lane; LDS dest = wave-uniform base + lane*16
__device__ __forceinline__ void gload16(const void* g, void* l) {
    __builtin_amdgcn_global_load_lds(
        (const __attribute__((address_space(1))) void*)g,
        (__attribute__((address_space(3))) void*)l,
        16, 0, 0);
}

// compiler-invisible LDS read (keeps waitcnt control out of the compiler)
#define DSREAD(dst, addr, off) \
    asm volatile("ds_read_b128 %0, %1 offset:" #off : "=v"(dst) : "v"(addr))

#define MM(i, j, a, w) \
    acc[i][j] = __builtin_amdgcn_mfma_f32_16x16x32_bf16(a, w, acc[i][j], 0, 0, 0)

// concat-K tile -> physical ushort offset (dedup: A phys = [hi|lo] K=1024,
// logical K=1536 = [hi|hi|lo]; W phys = [wh|wl], logical [wh|wl|wh])
__device__ __forceinline__ constexpr int atile(int t) {
    return t < 16 ? t * 32 : (t < 32 ? (t - 16) * 32 : 512 + (t - 32) * 32);
}
__device__ __forceinline__ constexpr int wtile(int t) {
    return t < 16 ? t * 32 : (t < 32 ? 512 + (t - 16) * 32 : (t - 32) * 32);
}

// ---------------------------------------------------------------------------
// Fused currents-GEMM + LIF recurrence.
// GRID: dim3(64,16), bx = blockIdx.x FAST-VARYING.  This is load-bearing:
// linear bid = bx + 64*by => xcd = bid%8 = bx%8, so each XCD owns a bx-STRIPE
// of A (8 panels ~ 2.6 MB, L2-resident across all by) and W panels are
// broadcast-fetched once per XCD.  Traffic model (validated R5/R6):
// A ~21 MB + W ~50 MB (dedup'd).  R6's by-per-XCD swizzle inverted this and
// thrashed L2 (A re-fetched 2x per XCD = 324 MB) -- do not reorder the grid.
// Dedup'd operands (A 10240x1024 [hi|lo], W 3072x1024 [wh|wl]) with
// compile-time tile remap in the fully-unrolled K-loop (same accumulation
// order as the logical [hi|hi|lo]x[wh|wl|wh] concat-K).
// Pipeline: 3 LDS bufs (67.5 KB -> 2 blocks/CU), dist-2 prefetch, per-wave
// counted vmcnt (4/8 steady, never 0 in-loop), asm ds_reads, counted
// lgkmcnt(4) interleave (row-0 MFMAs overlap remaining ds returns),
// 2 barriers/tile, setprio.  Epilogue: in-register LIF -> int8 counts.
// ---------------------------------------------------------------------------
__global__ __launch_bounds__(512, 4) void fused_cur_lif(
    const ushort_t* __restrict__ A, const ushort_t* __restrict__ W,
    const float* __restrict__ b123, const float* __restrict__ wl,
    const float* __restrict__ bl, signed char* __restrict__ xb)
{
    // [buf][ A: 160x32 (5120 us) | B: 192x32 (6144 us) ] = 22.5KB x 3
    __shared__ ushort_t lds[3][11264];

    const int t = threadIdx.x;
    const int bx = blockIdx.x;           // 0..63  (m: 32 batches each)  FAST
    const int by = blockIdx.y;           // 0..15  (n: 64 channels each) SLOW
    const int lane = t & 63;
    const int wv = t >> 6;
    const int wm = (wv >> 2) * 80;       // wave m-offset: 0 / 80
    const int wn = (wv & 3) * 48;        // wave n-offset: 0/48/96/144
    const int fr = lane & 15;
    const int fq = lane >> 4;
    const int swz16 = (fq ^ ((fr >> 1) & 3)) * 16;   // read swizzle, bytes

    // per-buffer ds_read base addresses (bytes); buffer stride 22528
    const unsigned av0 = (unsigned)((wm + fr) * 64 + swz16);
    const unsigned av1 = av0 + 22528;
    const unsigned av2 = av0 + 45056;
    const unsigned bv0 = (unsigned)(10240 + (wn + fr) * 64 + swz16);
    const unsigned bv1 = bv0 + 22528;
    const unsigned bv2 = bv0 + 45056;

    // staging role: waves 0-4 stage A (2 x 16-row groups), 5-7 stage B (4)
    const ushort_t* src0; const ushort_t* src1;
    const ushort_t* src2; const ushort_t* src3;
    int dst0, dst1, dst2, dst3;
    if (wv < 5) {
        const int rl0 = wv * 32 + (lane >> 2);
        const int rl1 = rl0 + 16;
        src0 = A + (size_t)(bx * 160 + rl0) * 1024 + ((lane & 3) ^ ((rl0 >> 1) & 3)) * 8;
        src1 = A + (size_t)(bx * 160 + rl1) * 1024 + ((lane & 3) ^ ((rl1 >> 1) & 3)) * 8;
        src2 = src0; src3 = src1;
        dst0 = rl0 * 32 + (lane & 3) * 8;
        dst1 = rl1 * 32 + (lane & 3) * 8;
        dst2 = dst0; dst3 = dst1;
    } else {
        const int rb = (wv - 5) * 64 + (lane >> 2);
        src0 = W + (size_t)(by * 192 + rb) * 1024 + ((lane & 3) ^ ((rb >> 1) & 3)) * 8;
        src1 = src0 + (size_t)16 * 1024;
        src2 = src0 + (size_t)32 * 1024;
        src3 = src0 + (size_t)48 * 1024;
        dst0 = 5120 + rb * 32 + (lane & 3) * 8;
        dst1 = dst0 + 16 * 32;
        dst2 = dst0 + 32 * 32;
        dst3 = dst0 + 48 * 32;
    }

#define STAGE(tile, sbuf)                                              \
    do {                                                               \
        ushort_t* lb_ = &lds[sbuf][0];                                 \
        if (wv < 5) {                                                  \
            gload16(src0 + atile(tile), lb_ + dst0);                   \
            gload16(src1 + atile(tile), lb_ + dst1);                   \
        } else {                                                       \
            gload16(src0 + wtile(tile), lb_ + dst0);                   \
            gload16(src1 + wtile(tile), lb_ + dst1);                   \
            gload16(src2 + wtile(tile), lb_ + dst2);                   \
            gload16(src3 + wtile(tile), lb_ + dst3);                   \
        }                                                              \
    } while (0)

#define COMPUTE(av_, bv_)                                              \
    do {                                                               \
        bf16x8 af0, af1, af2, af3, af4, wf0, wf1, wf2;                 \
        DSREAD(af0, av_, 0);                                           \
        DSREAD(wf0, bv_, 0);                                           \
        DSREAD(wf1, bv_, 1024);                                        \
        DSREAD(wf2, bv_, 2048);                                        \
        DSREAD(af1, av_, 1024);                                        \
        DSREAD(af2, av_, 2048);                                        \
        DSREAD(af3, av_, 3072);                                        \
        DSREAD(af4, av_, 4096);                                        \
        asm volatile("s_waitcnt lgkmcnt(4)" ::: "memory");             \
        __builtin_amdgcn_sched_barrier(0);                             \
        __builtin_amdgcn_s_setprio(1);                                 \
        MM(0, 0, af0, wf0); MM(0, 1, af0, wf1); MM(0, 2, af0, wf2);    \
        asm volatile("s_waitcnt lgkmcnt(0)" ::: "memory");             \
        __builtin_amdgcn_sched_barrier(0);                             \
        MM(1, 0, af1, wf0); MM(1, 1, af1, wf1); MM(1, 2, af1, wf2);    \
        MM(2, 0, af2, wf0); MM(2, 1, af2, wf1); MM(2, 2, af2, wf2);    \
        MM(3, 0, af3, wf0); MM(3, 1, af3, wf1); MM(3, 2, af3, wf2);    \
        MM(4, 0, af4, wf0); MM(4, 1, af4, wf1); MM(4, 2, af4, wf2);    \
        __builtin_amdgcn_s_setprio(0);                                 \
    } while (0)

    f32x4 acc[5][3];
#pragma unroll
    for (int i = 0; i < 5; i++)
#pragma unroll
        for (int j = 0; j < 3; j++) {
            f32x4 z = {0.f, 0.f, 0.f, 0.f};
            acc[i][j] = z;
        }

    // prologue: tiles 0,1 in flight
    STAGE(0, 0);
    STAGE(1, 1);

    // main loop, fully unrolled: tiles 0..45, staging 2..47
#pragma unroll
    for (int tt = 0; tt < 46; ++tt) {
        STAGE(tt + 2, (tt + 2) % 3);
        if (wv < 5) asm volatile("s_waitcnt vmcnt(4)" ::: "memory");
        else        asm volatile("s_waitcnt vmcnt(8)" ::: "memory");
        __builtin_amdgcn_s_barrier();
        __builtin_amdgcn_sched_barrier(0);
        const unsigned av_ = (tt % 3 == 0) ? av0 : (tt % 3 == 1) ? av1 : av2;
        const unsigned bv_ = (tt % 3 == 0) ? bv0 : (tt % 3 == 1) ? bv1 : bv2;
        COMPUTE(av_, bv_);
        __builtin_amdgcn_s_barrier();
        __builtin_amdgcn_sched_barrier(0);
    }
    // tt = 46 (buffer 1): only tile 47's loads still outstanding
    if (wv < 5) asm volatile("s_waitcnt vmcnt(2)" ::: "memory");
    else        asm volatile("s_waitcnt vmcnt(4)" ::: "memory");
    __builtin_amdgcn_s_barrier();
    __builtin_amdgcn_sched_barrier(0);
    COMPUTE(av1, bv1);
    __builtin_amdgcn_s_barrier();
    __builtin_amdgcn_sched_barrier(0);
    // tt = 47 (buffer 2): drain
    asm volatile("s_waitcnt vmcnt(0)" ::: "memory");
    __builtin_amdgcn_s_barrier();
    __builtin_amdgcn_sched_barrier(0);
    COMPUTE(av2, bv2);
#undef STAGE
#undef COMPUTE

    // ---- epilogue: in-register LIF recurrence (replaces recur_kernel) ----
    const int ch = by * 64 + (wv & 3) * 16 + fr;
    const float b1c = b123[ch];
    const float b2c = b123[1024 + ch];
    const float b3c = b123[2048 + ch];
    const float wl0 = wl[0], wl1 = wl[1], wl2 = wl[2], bl0 = bl[0];
    const int bbase = bx * 32 + (wv >> 2) * 16 + fq * 4;
#pragma unroll
    for (int r = 0; r < 4; r++) {
        float m0 = 0.f, m1 = 0.f, m2 = 0.f, m3 = 0.f;
        int s0 = 0, s1 = 0, s2 = 0, s3 = 0;
#pragma unroll
        for (int f = 0; f < 5; f++) {
            const float i1 = acc[f][0][r] + b1c;
            const float i2 = acc[f][1][r] + b2c;
            const float i3 = acc[f][2][r] + b3c;
#pragma unroll
            for (int rep = 0; rep < 3; rep++) {
                const float inner = m0 * wl0 + m1 * wl1 + m2 * wl2 + bl0;
                const float n0 = i1 + ((m0 > THRESH) ? 0.f : DECAY * m0);
                const float n1 = i2 + ((m1 > THRESH) ? 0.f : DECAY * m1);
                const float n2 = i3 + ((m2 > THRESH) ? 0.f : DECAY * m2);
                const float n3 = inner + ((m3 > THRESH) ? 0.f : DECAY * m3);
                m0 = n0; m1 = n1; m2 = n2; m3 = n3;
                s0 += (n0 > THRESH); s1 += (n1 > THRESH);
                s2 += (n2 > THRESH); s3 += (n3 > THRESH);
            }
        }
        uchar4 o;
        o.x = (unsigned char)s0; o.y = (unsigned char)s1;
        o.z = (unsigned char)s2; o.w = (unsigned char)s3;
        *(uchar4*)&xb[(size_t)(bbase + r) * 4096 + ch * 4] = o;
    }
}

// ---------------------------------------------------------------------------
// MLP layer 1, int8 MFMA at FULL rate (16x16x64, 16B frags).
// ---------------------------------------------------------------------------
__global__ __launch_bounds__(256) void mlp1_i8(
    const signed char* __restrict__ A, const signed char* __restrict__ W,
    const float* __restrict__ wsc, const float* __restrict__ bias,
    ushort_t* __restrict__ C)
{
    __shared__ signed char sA[64 * 64];    // 4 KB
    __shared__ signed char sW[128 * 64];   // 8 KB

    const int t = threadIdx.x;
    const int mBase = blockIdx.x * 64;
    const int nBase = blockIdx.y * 128;

    const int lane = t & 63;
    const int wv = t >> 6;
    const int wn = wv * 32;
    const int fr = lane & 15;
    const int fq = lane >> 4;            // k-offset = fq*16 bytes
    const int fsw = (fq ^ ((fr >> 1) & 3)) * 16;  // swizzled read chunk (bytes)

    const int r0 = t >> 2;                           // staging row 0..63
    const int cc = ((t & 3) ^ ((t >> 3) & 3)) * 16;  // pre-swizzled src byte-col

    i32x4 acc[4][2];
#pragma unroll
    for (int i = 0; i < 4; i++)
#pragma unroll
        for (int j = 0; j < 2; j++) {
            i32x4 z = {0, 0, 0, 0};
            acc[i][j] = z;
        }

    for (int k0 = 0; k0 < 4096; k0 += 64) {
        gload16(&A[(size_t)(mBase + r0) * 4096 + k0 + cc], &sA[t * 16]);
        gload16(&W[(size_t)(nBase + r0) * 4096 + k0 + cc], &sW[t * 16]);
        gload16(&W[(size_t)(nBase + 64 + r0) * 4096 + k0 + cc], &sW[4096 + t * 16]);
        __syncthreads();

        i32x4 af[4], wf[2];
#pragma unroll
        for (int i = 0; i < 4; i++)
            af[i] = *(const i32x4*)&sA[(i * 16 + fr) * 64 + fsw];
#pragma unroll
        for (int j = 0; j < 2; j++)
            wf[j] = *(const i32x4*)&sW[(wn + j * 16 + fr) * 64 + fsw];
#pragma unroll
        for (int i = 0; i < 4; i++)
#pragma unroll
            for (int j = 0; j < 2; j++)
                acc[i][j] = __builtin_amdgcn_mfma_i32_16x16x64_i8(af[i], wf[j], acc[i][j], 0, 0, 0);
        __syncthreads();
    }

#pragma unroll
    for (int j = 0; j < 2; j++) {
        const int col = nBase + wn + j * 16 + fr;
        const float sc = wsc[col];
        const float bv = bias[col];
#pragma unroll
        for (int i = 0; i < 4; i++)
#pragma unroll
            for (int r = 0; r < 4; r++) {
                const int row = mBase + i * 16 + fq * 4 + r;
                const float v = (float)acc[i][j][r] * sc + bv;
                C[(size_t)row * 2048 + col] = f2bf(fmaxf(v, 0.f));
            }
    }
}

// ---------------------------------------------------------------------------
// MLP layer 2: bf16, 64x128 tile, block-diagonal.
// ---------------------------------------------------------------------------
__global__ __launch_bounds__(256) void mlp2_bf16(
    const ushort_t* __restrict__ A, const ushort_t* __restrict__ W,
    const float* __restrict__ bias, ushort_t* __restrict__ C,
    int N, int K, int lda, int ldw, int ldc, int aHalfOff)
{
    __shared__ ushort_t sA[64 * 32];
    __shared__ ushort_t sW[128 * 32];

    const int t = threadIdx.x;
    const int mBase = blockIdx.x * 64;
    const int nBase = blockIdx.y * 128;
    const int aOff = (2 * nBase >= N) ? aHalfOff : 0;

    const int lane = t & 63;
    const int wv = t >> 6;
    const int wn = wv * 32;
    const int fr = lane & 15;
    const int fq = lane >> 4;
    const int fsw = (fq ^ ((fr >> 1) & 3)) * 8;   // swizzled read chunk (ushorts)

    const int r0 = t >> 2;                           // 0..63
    const int cc = ((t & 3) ^ ((t >> 3) & 3)) * 8;   // pre-swizzled src k-col

    f32x4 acc[4][2];
#pragma unroll
    for (int i = 0; i < 4; i++)
#pragma unroll
        for (int j = 0; j < 2; j++) {
            f32x4 z = {0.f, 0.f, 0.f, 0.f};
            acc[i][j] = z;
        }

    for (int k0 = 0; k0 < K; k0 += 32) {
        gload16(&A[(size_t)(mBase + r0) * lda + aOff + k0 + cc], &sA[t * 8]);
        gload16(&W[(size_t)(nBase + r0) * ldw + k0 + cc], &sW[t * 8]);
        gload16(&W[(size_t)(nBase + 64 + r0) * ldw + k0 + cc], &sW[2048 + t * 8]);
        __syncthreads();

        bf16x8 af[4], wf[2];
#pragma unroll
        for (int i = 0; i < 4; i++)
            af[i] = *(const bf16x8*)&sA[(i * 16 + fr) * 32 + fsw];
#pragma unroll
        for (int j = 0; j < 2; j++)
            wf[j] = *(const bf16x8*)&sW[(wn + j * 16 + fr) * 32 + fsw];
#pragma unroll
        for (int i = 0; i < 4; i++)
#pragma unroll
            for (int j = 0; j < 2; j++)
                acc[i][j] = __builtin_amdgcn_mfma_f32_16x16x32_bf16(af[i], wf[j], acc[i][j], 0, 0, 0);
        __syncthreads();
    }

#pragma unroll
    for (int j = 0; j < 2; j++) {
        const int col = nBase + wn + j * 16 + fr;
        const float bv = bias[col];
#pragma unroll
        for (int i = 0; i < 4; i++)
#pragma unroll
            for (int r = 0; r < 4; r++) {
                const int row = mBase + i * 16 + fq * 4 + r;
                C[(size_t)row * ldc + col] = f2bf(fmaxf(acc[i][j][r] + bv, 0.f));
            }
    }
}

// ---------------------------------------------------------------------------
// Consolidated prep:
//  - state -> A'' (row-permuted, phys K=1024 [hi|lo])
//  - w1/w2/w3 -> W'' (row-permuted, phys K=1024 [wh|wl])
//  - w11|w21 -> int8 rows with per-row scale (shuffle-based reduction)
//  - w12/w22 -> bf16; bias packing
// ---------------------------------------------------------------------------
__device__ __forceinline__ void split_state_perm(const float4* src, ushort4* dst,
                                                 int base, int t) {
#pragma unroll
    for (int p = 0; p < 4; p++) {
        const int i = base * 1024 + p * 256 + t;
        const float4 v = src[i];
        ushort4 h, l;
        h.x = f2bf(v.x); l.x = f2bf(v.x - bf2f(h.x));
        h.y = f2bf(v.y); l.y = f2bf(v.y - bf2f(h.y));
        h.z = f2bf(v.z); l.z = f2bf(v.z - bf2f(h.z));
        h.w = f2bf(v.w); l.w = f2bf(v.w - bf2f(h.w));
        const int s = i >> 7, c4 = i & 127;      // source row (b*5+f), f4-col
        const int b = s / 5, f = s - b * 5;
        const int m = ((b >> 5) * 160) + (((b >> 4) & 1) * 80) + (f << 4) + (b & 15);
        ushort4* row = dst + (size_t)m * 256;    // 1024 ushorts = 256 ushort4
        row[c4] = h; row[128 + c4] = l;          // [hi | lo]
    }
}
__device__ __forceinline__ void split_w_perm(const float4* src, ushort4* dst,
                                             int base, int t, int j) {
#pragma unroll
    for (int p = 0; p < 4; p++) {
        const int i = base * 1024 + p * 256 + t;
        const float4 v = src[i];
        ushort4 h, l;
        h.x = f2bf(v.x); l.x = f2bf(v.x - bf2f(h.x));
        h.y = f2bf(v.y); l.y = f2bf(v.y - bf2f(h.y));
        h.z = f2bf(v.z); l.z = f2bf(v.z - bf2f(h.z));
        h.w = f2bf(v.w); l.w = f2bf(v.w - bf2f(h.w));
        const int c = i >> 7, c4 = i & 127;      // source row (channel), f4-col
        const int n = ((c >> 6) * 192) + (((c >> 4) & 3) * 48) + (j << 4) + (c & 15);
        ushort4* row = dst + (size_t)n * 256;
        row[c4] = h; row[128 + c4] = l;          // [wh | wl]
    }
}
__device__ __forceinline__ void do_cvt4(const float4* src, ushort4* dst,
                                        int base, int t) {
#pragma unroll
    for (int p = 0; p < 4; p++) {
        const int i = base * 1024 + p * 256 + t;
        const float4 v = src[i];
        ushort4 h;
        h.x = f2bf(v.x); h.y = f2bf(v.y); h.z = f2bf(v.z); h.w = f2bf(v.w);
        dst[i] = h;
    }
}
__device__ __forceinline__ int q8(float x, float inv) {
    int q = (int)rintf(x * inv);
    q = q > 127 ? 127 : (q < -127 ? -127 : q);
    return q & 0xff;
}

__global__ __launch_bounds__(256) void prep_kernel(
    const float* __restrict__ state,
    const float* __restrict__ w1, const float* __restrict__ w2,
    const float* __restrict__ w3,
    const float* __restrict__ w11, const float* __restrict__ w21,
    const float* __restrict__ w12, const float* __restrict__ w22,
    const float* __restrict__ b1, const float* __restrict__ b2,
    const float* __restrict__ b3, const float* __restrict__ b11,
    const float* __restrict__ b21, const float* __restrict__ b12,
    const float* __restrict__ b22,
    ushort_t* __restrict__ Ap, ushort_t* __restrict__ Wp,
    signed char* __restrict__ w1q, float* __restrict__ wsc,
    ushort_t* __restrict__ w2b,
    float* __restrict__ b123, float* __restrict__ bb1, float* __restrict__ bb2)
{
    const int bid = blockIdx.x;
    const int t = threadIdx.x;
    if (bid < 1280) {
        split_state_perm((const float4*)state, (ushort4*)Ap, bid, t);
    } else if (bid < 1408) {
        split_w_perm((const float4*)w1, (ushort4*)Wp, bid - 1280, t, 0);
    } else if (bid < 1536) {
        split_w_perm((const float4*)w2, (ushort4*)Wp, bid - 1408, t, 1);
    } else if (bid < 1664) {
        split_w_perm((const float4*)w3, (ushort4*)Wp, bid - 1536, t, 2);
    } else if (bid < 3712) {
        // one block per output row of [w11 ; w21] -> int8 + per-row scale
        const int r = bid - 1664;
        const float* src = (r < 1024) ? (w11 + (size_t)r * 4096)
                                      : (w21 + (size_t)(r - 1024) * 4096);
        __shared__ float red4[4];
        float4 v[4];
        float lmax = 0.f;
#pragma unroll
        for (int p = 0; p < 4; p++) {
            v[p] = ((const float4*)src)[t * 4 + p];
            lmax = fmaxf(lmax, fmaxf(fmaxf(fabsf(v[p].x), fabsf(v[p].y)),
                                     fmaxf(fabsf(v[p].z), fabsf(v[p].w))));
        }
#pragma unroll
        for (int d = 1; d < 64; d <<= 1)
            lmax = fmaxf(lmax, __shfl_xor(lmax, d, 64));
        if ((t & 63) == 0) red4[t >> 6] = lmax;
        __syncthreads();
        const float gmax = fmaxf(fmaxf(fmaxf(red4[0], red4[1]),
                                       fmaxf(red4[2], red4[3])), 1e-30f);
        const float inv = 127.0f / gmax;
        int4 o;
        o.x = q8(v[0].x, inv) | (q8(v[0].y, inv) << 8) | (q8(v[0].z, inv) << 16) | (q8(v[0].w, inv) << 24);
        o.y = q8(v[1].x, inv) | (q8(v[1].y, inv) << 8) | (q8(v[1].z, inv) << 16) | (q8(v[1].w, inv) << 24);
        o.z = q8(v[2].x, inv) | (q8(v[2].y, inv) << 8) | (q8(v[2].z, inv) << 16) | (q8(v[2].w, inv) << 24);
        o.w = q8(v[3].x, inv) | (q8(v[3].y, inv) << 8) | (q8(v[3].z, inv) << 16) | (q8(v[3].w, inv) << 24);
        ((int4*)(w1q + (size_t)r * 4096))[t] = o;
        if (t == 0) wsc[r] = gmax / (127.0f * 15.0f);
    } else if (bid < 3968) {
        do_cvt4((const float4*)w12, (ushort4*)w2b, bid - 3712, t);
    } else if (bid < 4224) {
        do_cvt4((const float4*)w22, (ushort4*)(w2b + 1048576), bid - 3968, t);
    } else {
#pragma unroll
        for (int p = 0; p < 4; p++) {
            const int i = p * 256 + t;
            b123[i] = b1[i]; b123[1024 + i] = b2[i]; b123[2048 + i] = b3[i];
            bb1[i] = b11[i]; bb1[1024 + i] = b21[i];
            bb2[i] = b12[i]; bb2[1024 + i] = b22[i];
        }
    }
}

// ---------------------------------------------------------------------------
// Heads (both branches): out[b][n] = (clip?)(h2[b][off+k] . w[n][k] + bias[n])
// ---------------------------------------------------------------------------
__global__ __launch_bounds__(256) void head_kernel(
    const ushort_t* __restrict__ h, const float* __restrict__ wm,
    const float* __restrict__ bm, const float* __restrict__ ws,
    const float* __restrict__ bs, float* __restrict__ out)
{
    const int t = threadIdx.x;
    const int branch = blockIdx.x >> 8;
    const int n = t & 31;
    const int b = (blockIdx.x & 255) * 8 + (t >> 5);
    const ushort_t* hr = h + (size_t)b * 2048 + branch * 1024;
    const float* wr = (branch ? ws : wm) + (size_t)n * 1024;
    float s = 0.f;
#pragma unroll 4
    for (int k = 0; k < 1024; k += 8) {
        const uint4 hv = *(const uint4*)&hr[k];
        const float4 w0 = *(const float4*)&wr[k];
        const float4 w1 = *(const float4*)&wr[k + 4];
        s += blo(hv.x) * w0.x + bhi(hv.x) * w0.y
           + blo(hv.y) * w0.z + bhi(hv.y) * w0.w
           + blo(hv.z) * w1.x + bhi(hv.z) * w1.y
           + blo(hv.w) * w1.z + bhi(hv.w) * w1.w;
    }
    s += (branch ? bs : bm)[n];
    if (branch) s = fminf(fmaxf(s, -20.f), 2.f);
    out[(size_t)branch * 65536 + (size_t)b * 32 + n] = s;
}

// ---------------------------------------------------------------------------
extern "C" void kernel_launch(void* const* d_in, const int* in_sizes, int n_in,
                              void* d_out, int out_size, void* d_ws, size_t ws_size,
                              hipStream_t stream)
{
    const float* state = (const float*)d_in[0];
    const float* w1  = (const float*)d_in[1];  const float* b1  = (const float*)d_in[2];
    const float* w2  = (const float*)d_in[3];  const float* b2  = (const float*)d_in[4];
    const float* w3  = (const float*)d_in[5];  const float* b3  = (const float*)d_in[6];
    const float* wl  = (const float*)d_in[7];  const float* bl  = (const float*)d_in[8];
    const float* w11 = (const float*)d_in[9];  const float* b11 = (const float*)d_in[10];
    const float* w12 = (const float*)d_in[11]; const float* b12 = (const float*)d_in[12];
    const float* w21 = (const float*)d_in[13]; const float* b21 = (const float*)d_in[14];
    const float* w22 = (const float*)d_in[15]; const float* b22 = (const float*)d_in[16];
    const float* wm  = (const float*)d_in[17]; const float* bm  = (const float*)d_in[18];
    const float* ws  = (const float*)d_in[19]; const float* bs  = (const float*)d_in[20];
    float* out = (float*)d_out;

    // ---- workspace layout ----
    char* wp = (char*)d_ws;
    ushort_t*    Ap    = (ushort_t*)wp;    wp += (size_t)10240 * 1024 * 2;   // 21MB
    ushort_t*    Wp    = (ushort_t*)wp;    wp += (size_t)3072 * 1024 * 2;    // 6.3MB
    signed char* xb    = (signed char*)wp; wp += (size_t)2048 * 4096;        // int8 counts
    signed char* w1q   = (signed char*)wp; wp += (size_t)2048 * 4096;        // int8 [w11;w21]
    ushort_t*    w2b   = (ushort_t*)wp;    wp += (size_t)2048 * 1024 * 2;
    ushort_t*    h1    = (ushort_t*)wp;    wp += (size_t)2048 * 2048 * 2;
    ushort_t*    h2    = (ushort_t*)wp;    wp += (size_t)2048 * 2048 * 2;
    float*       wsc   = (float*)wp;       wp += 2048 * 4;
    float*       b123  = (float*)wp;       wp += 3072 * 4;
    float*       bb1   = (float*)wp;       wp += 2048 * 4;
    float*       bb2   = (float*)wp;       wp += 2048 * 4;

    // ---- prep: permuted splits (dedup'd), int8 quant, cvts, bias packing ----
    prep_kernel<<<4225, 256, 0, stream>>>(
        state, w1, w2, w3, w11, w21, w12, w22,
        b1, b2, b3, b11, b21, b12, b22,
        Ap, Wp, w1q, wsc, w2b, b123, bb1, bb2);

    // ---- fused currents GEMM + LIF -> spike counts int8 [2048, 4096] ----
    // grid (64,16): bx fast-varying => per-XCD bx-striping (see kernel note)
    fused_cur_lif<<<dim3(64, 16), 512, 0, stream>>>(Ap, Wp, b123, wl, bl, xb);

    // ---- MLP layer 1 (both branches) i8 K=64 MFMA, 512 blocks ----
    mlp1_i8<<<dim3(32, 16), 256, 0, stream>>>(xb, w1q, wsc, bb1, h1);

    // ---- MLP layer 2 (block-diagonal) bf16, 512 blocks ----
    mlp2_bf16<<<dim3(32, 16), 256, 0, stream>>>(
        h1, w2b, bb2, h2, 2048, 1024, 2048, 1024, 2048, 1024);

    // ---- heads (both branches) ----
    head_kernel<<<512, 256, 0, stream>>>(h2, wm, bm, ws, bs, out);
}

// Round 8
// 368.374 us; speedup vs baseline: 1.0844x; 1.0482x over previous
//
#include <hip/hip_runtime.h>
#include <cstddef>
#include <cstdint>

#define THRESH 0.8f
#define DECAY  0.2f

typedef unsigned short ushort_t;
typedef __attribute__((ext_vector_type(8))) short bf16x8;
typedef __attribute__((ext_vector_type(4))) float f32x4;
typedef __attribute__((ext_vector_type(4))) int i32x4;   // also 16 x i8 operand

__device__ __forceinline__ ushort_t f2bf(float f) {
    union { float f; unsigned u; } v; v.f = f;
    unsigned r = v.u + 0x7FFFu + ((v.u >> 16) & 1u);
    return (ushort_t)(r >> 16);
}
__device__ __forceinline__ float bf2f(ushort_t h) {
    union { unsigned u; float f; } v; v.u = ((unsigned)h) << 16;
    return v.f;
}
__device__ __forceinline__ float blo(unsigned u) {
    union { unsigned x; float f; } v; v.x = u << 16; return v.f;
}
__device__ __forceinline__ float bhi(unsigned u) {
    union { unsigned x; float f; } v; v.x = u & 0xFFFF0000u; return v.f;
}

// async global->LDS, 16B per lane; LDS dest = wave-uniform base + lane*16
__device__ __forceinline__ void gload16(const void* g, void* l) {
    __builtin_amdgcn_global_load_lds(
        (const __attribute__((address_space(1))) void*)g,
        (__attribute__((address_space(3))) void*)l,
        16, 0, 0);
}

// compiler-invisible LDS read (keeps waitcnt control out of the compiler)
#define DSREAD(dst, addr, off) \
    asm volatile("ds_read_b128 %0, %1 offset:" #off : "=v"(dst) : "v"(addr))

#define MM(i, j, a, w) \
    acc[i][j] = __builtin_amdgcn_mfma_f32_16x16x32_bf16(a, w, acc[i][j], 0, 0, 0)

// ---------------------------------------------------------------------------
// Fused currents-GEMM + LIF recurrence -- REVERTED to the R5 configuration,
// the best-measured state (121 us, FETCH 91 MB, WRITE 32 MB).
//
// Two measured DO-NOTs are baked in here (R6/R7 post-mortems):
//  (1) GRID dim3(64,16), bx fast-varying, is load-bearing: xcd = bid%8 =
//      bx%8 stripes A panels per-XCD (L2-resident across all by); the
//      by-per-XCD swizzle thrashed L2 (FETCH 91 -> 324 MB).
//  (2) Operands are deliberately NOT dedup'd: A' = [Ah|Ah|Al] (K=1536),
//      W' = [Wh|Wl|Wh].  A "dedup" to K=1024 with a tile remap re-reads
//      the same bytes 16 tiles later -> evicted -> re-fetched from HBM
//      (FETCH 91 -> 134 MB, dur 121 -> 214 us).  Three distinct streamed
//      regions beat one re-read region.
//
// Structure: tile 160x192, 8 waves (2m x 4n), per-wave 80x48 = acc[5][3];
// with the prep row-permutations, lane (fq,fr) holds all 15 currents for
// 4 batches x 1 channel -> LIF runs in-register in the epilogue and writes
// int8 spike counts directly (cur + recur_kernel eliminated).
// Pipeline: 3 LDS bufs (67.5 KB -> 2 blocks/CU), dist-2 prefetch, per-wave
// counted vmcnt (4/8 steady, never 0 in-loop), asm ds_reads + single
// lgkmcnt(0) fence (rule #18), 2 barriers/tile, setprio, fully-unrolled
// K-loop (all addresses compile-time).
// ---------------------------------------------------------------------------
__global__ __launch_bounds__(512, 4) void fused_cur_lif(
    const ushort_t* __restrict__ A, const ushort_t* __restrict__ W,
    const float* __restrict__ b123, const float* __restrict__ wl,
    const float* __restrict__ bl, signed char* __restrict__ xb)
{
    // [buf][ A: 160x32 (5120 us) | B: 192x32 (6144 us) ] = 22.5KB x 3
    __shared__ ushort_t lds[3][11264];

    const int t = threadIdx.x;
    const int bx = blockIdx.x;           // 0..63  (m: 32 batches each)  FAST
    const int by = blockIdx.y;           // 0..15  (n: 64 channels each) SLOW
    const int lane = t & 63;
    const int wv = t >> 6;
    const int wm = (wv >> 2) * 80;       // wave m-offset: 0 / 80
    const int wn = (wv & 3) * 48;        // wave n-offset: 0/48/96/144
    const int fr = lane & 15;
    const int fq = lane >> 4;
    const int swz16 = (fq ^ ((fr >> 1) & 3)) * 16;   // read swizzle, bytes

    // per-buffer ds_read base addresses (bytes); buffer stride 22528
    const unsigned av0 = (unsigned)((wm + fr) * 64 + swz16);
    const unsigned av1 = av0 + 22528;
    const unsigned av2 = av0 + 45056;
    const unsigned bv0 = (unsigned)(10240 + (wn + fr) * 64 + swz16);
    const unsigned bv1 = bv0 + 22528;
    const unsigned bv2 = bv0 + 45056;

    // staging role: waves 0-4 stage A (2 x 16-row groups), 5-7 stage B (4)
    const ushort_t* src0; const ushort_t* src1;
    const ushort_t* src2; const ushort_t* src3;
    int dst0, dst1, dst2, dst3;
    if (wv < 5) {
        const int rl0 = wv * 32 + (lane >> 2);
        const int rl1 = rl0 + 16;
        src0 = A + (size_t)(bx * 160 + rl0) * 1536 + ((lane & 3) ^ ((rl0 >> 1) & 3)) * 8;
        src1 = A + (size_t)(bx * 160 + rl1) * 1536 + ((lane & 3) ^ ((rl1 >> 1) & 3)) * 8;
        src2 = src0; src3 = src1;
        dst0 = rl0 * 32 + (lane & 3) * 8;
        dst1 = rl1 * 32 + (lane & 3) * 8;
        dst2 = dst0; dst3 = dst1;
    } else {
        const int rb = (wv - 5) * 64 + (lane >> 2);
        src0 = W + (size_t)(by * 192 + rb) * 1536 + ((lane & 3) ^ ((rb >> 1) & 3)) * 8;
        src1 = src0 + (size_t)16 * 1536;
        src2 = src0 + (size_t)32 * 1536;
        src3 = src0 + (size_t)48 * 1536;
        dst0 = 5120 + rb * 32 + (lane & 3) * 8;
        dst1 = dst0 + 16 * 32;
        dst2 = dst0 + 32 * 32;
        dst3 = dst0 + 48 * 32;
    }

#define STAGE(tile, sbuf)                                              \
    do {                                                               \
        ushort_t* lb_ = &lds[sbuf][0];                                 \
        if (wv < 5) {                                                  \
            gload16(src0 + (tile) * 32, lb_ + dst0);                   \
            gload16(src1 + (tile) * 32, lb_ + dst1);                   \
        } else {                                                       \
            gload16(src0 + (tile) * 32, lb_ + dst0);                   \
            gload16(src1 + (tile) * 32, lb_ + dst1);                   \
            gload16(src2 + (tile) * 32, lb_ + dst2);                   \
            gload16(src3 + (tile) * 32, lb_ + dst3);                   \
        }                                                              \
    } while (0)

#define COMPUTE(av_, bv_)                                              \
    do {                                                               \
        bf16x8 af0, af1, af2, af3, af4, wf0, wf1, wf2;                 \
        DSREAD(af0, av_, 0);                                           \
        DSREAD(af1, av_, 1024);                                        \
        DSREAD(af2, av_, 2048);                                        \
        DSREAD(af3, av_, 3072);                                        \
        DSREAD(af4, av_, 4096);                                        \
        DSREAD(wf0, bv_, 0);                                           \
        DSREAD(wf1, bv_, 1024);                                        \
        DSREAD(wf2, bv_, 2048);                                        \
        asm volatile("s_waitcnt lgkmcnt(0)" ::: "memory");             \
        __builtin_amdgcn_sched_barrier(0);                             \
        __builtin_amdgcn_s_setprio(1);                                 \
        MM(0, 0, af0, wf0); MM(0, 1, af0, wf1); MM(0, 2, af0, wf2);    \
        MM(1, 0, af1, wf0); MM(1, 1, af1, wf1); MM(1, 2, af1, wf2);    \
        MM(2, 0, af2, wf0); MM(2, 1, af2, wf1); MM(2, 2, af2, wf2);    \
        MM(3, 0, af3, wf0); MM(3, 1, af3, wf1); MM(3, 2, af3, wf2);    \
        MM(4, 0, af4, wf0); MM(4, 1, af4, wf1); MM(4, 2, af4, wf2);    \
        __builtin_amdgcn_s_setprio(0);                                 \
    } while (0)

    f32x4 acc[5][3];
#pragma unroll
    for (int i = 0; i < 5; i++)
#pragma unroll
        for (int j = 0; j < 3; j++) {
            f32x4 z = {0.f, 0.f, 0.f, 0.f};
            acc[i][j] = z;
        }

    // prologue: tiles 0,1 in flight
    STAGE(0, 0);
    STAGE(1, 1);

    // main loop, fully unrolled: tiles 0..45, staging 2..47
#pragma unroll
    for (int tt = 0; tt < 46; ++tt) {
        STAGE(tt + 2, (tt + 2) % 3);
        if (wv < 5) asm volatile("s_waitcnt vmcnt(4)" ::: "memory");
        else        asm volatile("s_waitcnt vmcnt(8)" ::: "memory");
        __builtin_amdgcn_s_barrier();
        __builtin_amdgcn_sched_barrier(0);
        const unsigned av_ = (tt % 3 == 0) ? av0 : (tt % 3 == 1) ? av1 : av2;
        const unsigned bv_ = (tt % 3 == 0) ? bv0 : (tt % 3 == 1) ? bv1 : bv2;
        COMPUTE(av_, bv_);
        __builtin_amdgcn_s_barrier();
        __builtin_amdgcn_sched_barrier(0);
    }
    // tt = 46 (buffer 1): only tile 47's loads still outstanding
    if (wv < 5) asm volatile("s_waitcnt vmcnt(2)" ::: "memory");
    else        asm volatile("s_waitcnt vmcnt(4)" ::: "memory");
    __builtin_amdgcn_s_barrier();
    __builtin_amdgcn_sched_barrier(0);
    COMPUTE(av1, bv1);
    __builtin_amdgcn_s_barrier();
    __builtin_amdgcn_sched_barrier(0);
    // tt = 47 (buffer 2): drain
    asm volatile("s_waitcnt vmcnt(0)" ::: "memory");
    __builtin_amdgcn_s_barrier();
    __builtin_amdgcn_sched_barrier(0);
    COMPUTE(av2, bv2);
#undef STAGE
#undef COMPUTE

    // ---- epilogue: in-register LIF recurrence (replaces recur_kernel) ----
    const int ch = by * 64 + (wv & 3) * 16 + fr;
    const float b1c = b123[ch];
    const float b2c = b123[1024 + ch];
    const float b3c = b123[2048 + ch];
    const float wl0 = wl[0], wl1 = wl[1], wl2 = wl[2], bl0 = bl[0];
    const int bbase = bx * 32 + (wv >> 2) * 16 + fq * 4;
#pragma unroll
    for (int r = 0; r < 4; r++) {
        float m0 = 0.f, m1 = 0.f, m2 = 0.f, m3 = 0.f;
        int s0 = 0, s1 = 0, s2 = 0, s3 = 0;
#pragma unroll
        for (int f = 0; f < 5; f++) {
            const float i1 = acc[f][0][r] + b1c;
            const float i2 = acc[f][1][r] + b2c;
            const float i3 = acc[f][2][r] + b3c;
#pragma unroll
            for (int rep = 0; rep < 3; rep++) {
                const float inner = m0 * wl0 + m1 * wl1 + m2 * wl2 + bl0;
                const float n0 = i1 + ((m0 > THRESH) ? 0.f : DECAY * m0);
                const float n1 = i2 + ((m1 > THRESH) ? 0.f : DECAY * m1);
                const float n2 = i3 + ((m2 > THRESH) ? 0.f : DECAY * m2);
                const float n3 = inner + ((m3 > THRESH) ? 0.f : DECAY * m3);
                m0 = n0; m1 = n1; m2 = n2; m3 = n3;
                s0 += (n0 > THRESH); s1 += (n1 > THRESH);
                s2 += (n2 > THRESH); s3 += (n3 > THRESH);
            }
        }
        uchar4 o;
        o.x = (unsigned char)s0; o.y = (unsigned char)s1;
        o.z = (unsigned char)s2; o.w = (unsigned char)s3;
        *(uchar4*)&xb[(size_t)(bbase + r) * 4096 + ch * 4] = o;
    }
}

// ---------------------------------------------------------------------------
// MLP layer 1, int8 MFMA at FULL rate (16x16x64, 16B frags).
// ---------------------------------------------------------------------------
__global__ __launch_bounds__(256) void mlp1_i8(
    const signed char* __restrict__ A, const signed char* __restrict__ W,
    const float* __restrict__ wsc, const float* __restrict__ bias,
    ushort_t* __restrict__ C)
{
    __shared__ signed char sA[64 * 64];    // 4 KB
    __shared__ signed char sW[128 * 64];   // 8 KB

    const int t = threadIdx.x;
    const int mBase = blockIdx.x * 64;
    const int nBase = blockIdx.y * 128;

    const int lane = t & 63;
    const int wv = t >> 6;
    const int wn = wv * 32;
    const int fr = lane & 15;
    const int fq = lane >> 4;            // k-offset = fq*16 bytes
    const int fsw = (fq ^ ((fr >> 1) & 3)) * 16;  // swizzled read chunk (bytes)

    const int r0 = t >> 2;                           // staging row 0..63
    const int cc = ((t & 3) ^ ((t >> 3) & 3)) * 16;  // pre-swizzled src byte-col

    i32x4 acc[4][2];
#pragma unroll
    for (int i = 0; i < 4; i++)
#pragma unroll
        for (int j = 0; j < 2; j++) {
            i32x4 z = {0, 0, 0, 0};
            acc[i][j] = z;
        }

    for (int k0 = 0; k0 < 4096; k0 += 64) {
        gload16(&A[(size_t)(mBase + r0) * 4096 + k0 + cc], &sA[t * 16]);
        gload16(&W[(size_t)(nBase + r0) * 4096 + k0 + cc], &sW[t * 16]);
        gload16(&W[(size_t)(nBase + 64 + r0) * 4096 + k0 + cc], &sW[4096 + t * 16]);
        __syncthreads();

        i32x4 af[4], wf[2];
#pragma unroll
        for (int i = 0; i < 4; i++)
            af[i] = *(const i32x4*)&sA[(i * 16 + fr) * 64 + fsw];
#pragma unroll
        for (int j = 0; j < 2; j++)
            wf[j] = *(const i32x4*)&sW[(wn + j * 16 + fr) * 64 + fsw];
#pragma unroll
        for (int i = 0; i < 4; i++)
#pragma unroll
            for (int j = 0; j < 2; j++)
                acc[i][j] = __builtin_amdgcn_mfma_i32_16x16x64_i8(af[i], wf[j], acc[i][j], 0, 0, 0);
        __syncthreads();
    }

#pragma unroll
    for (int j = 0; j < 2; j++) {
        const int col = nBase + wn + j * 16 + fr;
        const float sc = wsc[col];
        const float bv = bias[col];
#pragma unroll
        for (int i = 0; i < 4; i++)
#pragma unroll
            for (int r = 0; r < 4; r++) {
                const int row = mBase + i * 16 + fq * 4 + r;
                const float v = (float)acc[i][j][r] * sc + bv;
                C[(size_t)row * 2048 + col] = f2bf(fmaxf(v, 0.f));
            }
    }
}

// ---------------------------------------------------------------------------
// MLP layer 2: bf16, 64x128 tile, block-diagonal.
// ---------------------------------------------------------------------------
__global__ __launch_bounds__(256) void mlp2_bf16(
    const ushort_t* __restrict__ A, const ushort_t* __restrict__ W,
    const float* __restrict__ bias, ushort_t* __restrict__ C,
    int N, int K, int lda, int ldw, int ldc, int aHalfOff)
{
    __shared__ ushort_t sA[64 * 32];
    __shared__ ushort_t sW[128 * 32];

    const int t = threadIdx.x;
    const int mBase = blockIdx.x * 64;
    const int nBase = blockIdx.y * 128;
    const int aOff = (2 * nBase >= N) ? aHalfOff : 0;

    const int lane = t & 63;
    const int wv = t >> 6;
    const int wn = wv * 32;
    const int fr = lane & 15;
    const int fq = lane >> 4;
    const int fsw = (fq ^ ((fr >> 1) & 3)) * 8;   // swizzled read chunk (ushorts)

    const int r0 = t >> 2;                           // 0..63
    const int cc = ((t & 3) ^ ((t >> 3) & 3)) * 8;   // pre-swizzled src k-col

    f32x4 acc[4][2];
#pragma unroll
    for (int i = 0; i < 4; i++)
#pragma unroll
        for (int j = 0; j < 2; j++) {
            f32x4 z = {0.f, 0.f, 0.f, 0.f};
            acc[i][j] = z;
        }

    for (int k0 = 0; k0 < K; k0 += 32) {
        gload16(&A[(size_t)(mBase + r0) * lda + aOff + k0 + cc], &sA[t * 8]);
        gload16(&W[(size_t)(nBase + r0) * ldw + k0 + cc], &sW[t * 8]);
        gload16(&W[(size_t)(nBase + 64 + r0) * ldw + k0 + cc], &sW[2048 + t * 8]);
        __syncthreads();

        bf16x8 af[4], wf[2];
#pragma unroll
        for (int i = 0; i < 4; i++)
            af[i] = *(const bf16x8*)&sA[(i * 16 + fr) * 32 + fsw];
#pragma unroll
        for (int j = 0; j < 2; j++)
            wf[j] = *(const bf16x8*)&sW[(wn + j * 16 + fr) * 32 + fsw];
#pragma unroll
        for (int i = 0; i < 4; i++)
#pragma unroll
            for (int j = 0; j < 2; j++)
                acc[i][j] = __builtin_amdgcn_mfma_f32_16x16x32_bf16(af[i], wf[j], acc[i][j], 0, 0, 0);
        __syncthreads();
    }

#pragma unroll
    for (int j = 0; j < 2; j++) {
        const int col = nBase + wn + j * 16 + fr;
        const float bv = bias[col];
#pragma unroll
        for (int i = 0; i < 4; i++)
#pragma unroll
            for (int r = 0; r < 4; r++) {
                const int row = mBase + i * 16 + fq * 4 + r;
                C[(size_t)row * ldc + col] = f2bf(fmaxf(acc[i][j][r] + bv, 0.f));
            }
    }
}

// ---------------------------------------------------------------------------
// Consolidated prep:
//  - state -> A'' (row-permuted, K-concat [hi|hi|lo], 1536-wide -- see the
//    fused kernel's DO-NOT note (2): deliberately NOT dedup'd)
//  - w1/w2/w3 -> W'' (row-permuted, K-concat [hi|lo|hi])
//  - w11|w21 -> int8 rows with per-row scale (shuffle-based reduction)
//  - w12/w22 -> bf16; bias packing
// ---------------------------------------------------------------------------
__device__ __forceinline__ void split_state_perm(const float4* src, ushort4* dst,
                                                 int base, int t) {
#pragma unroll
    for (int p = 0; p < 4; p++) {
        const int i = base * 1024 + p * 256 + t;
        const float4 v = src[i];
        ushort4 h, l;
        h.x = f2bf(v.x); l.x = f2bf(v.x - bf2f(h.x));
        h.y = f2bf(v.y); l.y = f2bf(v.y - bf2f(h.y));
        h.z = f2bf(v.z); l.z = f2bf(v.z - bf2f(h.z));
        h.w = f2bf(v.w); l.w = f2bf(v.w - bf2f(h.w));
        const int s = i >> 7, c4 = i & 127;      // source row (b*5+f), f4-col
        const int b = s / 5, f = s - b * 5;
        const int m = ((b >> 5) * 160) + (((b >> 4) & 1) * 80) + (f << 4) + (b & 15);
        ushort4* row = dst + (size_t)m * 384;    // 1536 ushorts = 384 ushort4
        row[c4] = h; row[128 + c4] = h; row[256 + c4] = l;   // [hi|hi|lo]
    }
}
__device__ __forceinline__ void split_w_perm(const float4* src, ushort4* dst,
                                             int base, int t, int j) {
#pragma unroll
    for (int p = 0; p < 4; p++) {
        const int i = base * 1024 + p * 256 + t;
        const float4 v = src[i];
        ushort4 h, l;
        h.x = f2bf(v.x); l.x = f2bf(v.x - bf2f(h.x));
        h.y = f2bf(v.y); l.y = f2bf(v.y - bf2f(h.y));
        h.z = f2bf(v.z); l.z = f2bf(v.z - bf2f(h.z));
        h.w = f2bf(v.w); l.w = f2bf(v.w - bf2f(h.w));
        const int c = i >> 7, c4 = i & 127;      // source row (channel), f4-col
        const int n = ((c >> 6) * 192) + (((c >> 4) & 3) * 48) + (j << 4) + (c & 15);
        ushort4* row = dst + (size_t)n * 384;
        row[c4] = h; row[128 + c4] = l; row[256 + c4] = h;   // [hi|lo|hi]
    }
}
__device__ __forceinline__ void do_cvt4(const float4* src, ushort4* dst,
                                        int base, int t) {
#pragma unroll
    for (int p = 0; p < 4; p++) {
        const int i = base * 1024 + p * 256 + t;
        const float4 v = src[i];
        ushort4 h;
        h.x = f2bf(v.x); h.y = f2bf(v.y); h.z = f2bf(v.z); h.w = f2bf(v.w);
        dst[i] = h;
    }
}
__device__ __forceinline__ int q8(float x, float inv) {
    int q = (int)rintf(x * inv);
    q = q > 127 ? 127 : (q < -127 ? -127 : q);
    return q & 0xff;
}

__global__ __launch_bounds__(256) void prep_kernel(
    const float* __restrict__ state,
    const float* __restrict__ w1, const float* __restrict__ w2,
    const float* __restrict__ w3,
    const float* __restrict__ w11, const float* __restrict__ w21,
    const float* __restrict__ w12, const float* __restrict__ w22,
    const float* __restrict__ b1, const float* __restrict__ b2,
    const float* __restrict__ b3, const float* __restrict__ b11,
    const float* __restrict__ b21, const float* __restrict__ b12,
    const float* __restrict__ b22,
    ushort_t* __restrict__ Ap, ushort_t* __restrict__ Wp,
    signed char* __restrict__ w1q, float* __restrict__ wsc,
    ushort_t* __restrict__ w2b,
    float* __restrict__ b123, float* __restrict__ bb1, float* __restrict__ bb2)
{
    const int bid = blockIdx.x;
    const int t = threadIdx.x;
    if (bid < 1280) {
        split_state_perm((const float4*)state, (ushort4*)Ap, bid, t);
    } else if (bid < 1408) {
        split_w_perm((const float4*)w1, (ushort4*)Wp, bid - 1280, t, 0);
    } else if (bid < 1536) {
        split_w_perm((const float4*)w2, (ushort4*)Wp, bid - 1408, t, 1);
    } else if (bid < 1664) {
        split_w_perm((const float4*)w3, (ushort4*)Wp, bid - 1536, t, 2);
    } else if (bid < 3712) {
        // one block per output row of [w11 ; w21] -> int8 + per-row scale
        const int r = bid - 1664;
        const float* src = (r < 1024) ? (w11 + (size_t)r * 4096)
                                      : (w21 + (size_t)(r - 1024) * 4096);
        __shared__ float red4[4];
        float4 v[4];
        float lmax = 0.f;
#pragma unroll
        for (int p = 0; p < 4; p++) {
            v[p] = ((const float4*)src)[t * 4 + p];
            lmax = fmaxf(lmax, fmaxf(fmaxf(fabsf(v[p].x), fabsf(v[p].y)),
                                     fmaxf(fabsf(v[p].z), fabsf(v[p].w))));
        }
#pragma unroll
        for (int d = 1; d < 64; d <<= 1)
            lmax = fmaxf(lmax, __shfl_xor(lmax, d, 64));
        if ((t & 63) == 0) red4[t >> 6] = lmax;
        __syncthreads();
        const float gmax = fmaxf(fmaxf(fmaxf(red4[0], red4[1]),
                                       fmaxf(red4[2], red4[3])), 1e-30f);
        const float inv = 127.0f / gmax;
        int4 o;
        o.x = q8(v[0].x, inv) | (q8(v[0].y, inv) << 8) | (q8(v[0].z, inv) << 16) | (q8(v[0].w, inv) << 24);
        o.y = q8(v[1].x, inv) | (q8(v[1].y, inv) << 8) | (q8(v[1].z, inv) << 16) | (q8(v[1].w, inv) << 24);
        o.z = q8(v[2].x, inv) | (q8(v[2].y, inv) << 8) | (q8(v[2].z, inv) << 16) | (q8(v[2].w, inv) << 24);
        o.w = q8(v[3].x, inv) | (q8(v[3].y, inv) << 8) | (q8(v[3].z, inv) << 16) | (q8(v[3].w, inv) << 24);
        ((int4*)(w1q + (size_t)r * 4096))[t] = o;
        if (t == 0) wsc[r] = gmax / (127.0f * 15.0f);
    } else if (bid < 3968) {
        do_cvt4((const float4*)w12, (ushort4*)w2b, bid - 3712, t);
    } else if (bid < 4224) {
        do_cvt4((const float4*)w22, (ushort4*)(w2b + 1048576), bid - 3968, t);
    } else {
#pragma unroll
        for (int p = 0; p < 4; p++) {
            const int i = p * 256 + t;
            b123[i] = b1[i]; b123[1024 + i] = b2[i]; b123[2048 + i] = b3[i];
            bb1[i] = b11[i]; bb1[1024 + i] = b21[i];
            bb2[i] = b12[i]; bb2[1024 + i] = b22[i];
        }
    }
}

// ---------------------------------------------------------------------------
// Heads (both branches): out[b][n] = (clip?)(h2[b][off+k] . w[n][k] + bias[n])
// ---------------------------------------------------------------------------
__global__ __launch_bounds__(256) void head_kernel(
    const ushort_t* __restrict__ h, const float* __restrict__ wm,
    const float* __restrict__ bm, const float* __restrict__ ws,
    const float* __restrict__ bs, float* __restrict__ out)
{
    const int t = threadIdx.x;
    const int branch = blockIdx.x >> 8;
    const int n = t & 31;
    const int b = (blockIdx.x & 255) * 8 + (t >> 5);
    const ushort_t* hr = h + (size_t)b * 2048 + branch * 1024;
    const float* wr = (branch ? ws : wm) + (size_t)n * 1024;
    float s = 0.f;
#pragma unroll 4
    for (int k = 0; k < 1024; k += 8) {
        const uint4 hv = *(const uint4*)&hr[k];
        const float4 w0 = *(const float4*)&wr[k];
        const float4 w1 = *(const float4*)&wr[k + 4];
        s += blo(hv.x) * w0.x + bhi(hv.x) * w0.y
           + blo(hv.y) * w0.z + bhi(hv.y) * w0.w
           + blo(hv.z) * w1.x + bhi(hv.z) * w1.y
           + blo(hv.w) * w1.z + bhi(hv.w) * w1.w;
    }
    s += (branch ? bs : bm)[n];
    if (branch) s = fminf(fmaxf(s, -20.f), 2.f);
    out[(size_t)branch * 65536 + (size_t)b * 32 + n] = s;
}

// ---------------------------------------------------------------------------
extern "C" void kernel_launch(void* const* d_in, const int* in_sizes, int n_in,
                              void* d_out, int out_size, void* d_ws, size_t ws_size,
                              hipStream_t stream)
{
    const float* state = (const float*)d_in[0];
    const float* w1  = (const float*)d_in[1];  const float* b1  = (const float*)d_in[2];
    const float* w2  = (const float*)d_in[3];  const float* b2  = (const float*)d_in[4];
    const float* w3  = (const float*)d_in[5];  const float* b3  = (const float*)d_in[6];
    const float* wl  = (const float*)d_in[7];  const float* bl  = (const float*)d_in[8];
    const float* w11 = (const float*)d_in[9];  const float* b11 = (const float*)d_in[10];
    const float* w12 = (const float*)d_in[11]; const float* b12 = (const float*)d_in[12];
    const float* w21 = (const float*)d_in[13]; const float* b21 = (const float*)d_in[14];
    const float* w22 = (const float*)d_in[15]; const float* b22 = (const float*)d_in[16];
    const float* wm  = (const float*)d_in[17]; const float* bm  = (const float*)d_in[18];
    const float* ws  = (const float*)d_in[19]; const float* bs  = (const float*)d_in[20];
    float* out = (float*)d_out;

    // ---- workspace layout ----
    char* wp = (char*)d_ws;
    ushort_t*    Ap    = (ushort_t*)wp;    wp += (size_t)10240 * 1536 * 2;   // 31.5MB
    ushort_t*    Wp    = (ushort_t*)wp;    wp += (size_t)3072 * 1536 * 2;    // 9.4MB
    signed char* xb    = (signed char*)wp; wp += (size_t)2048 * 4096;        // int8 counts
    signed char* w1q   = (signed char*)wp; wp += (size_t)2048 * 4096;        // int8 [w11;w21]
    ushort_t*    w2b   = (ushort_t*)wp;    wp += (size_t)2048 * 1024 * 2;
    ushort_t*    h1    = (ushort_t*)wp;    wp += (size_t)2048 * 2048 * 2;
    ushort_t*    h2    = (ushort_t*)wp;    wp += (size_t)2048 * 2048 * 2;
    float*       wsc   = (float*)wp;       wp += 2048 * 4;
    float*       b123  = (float*)wp;       wp += 3072 * 4;
    float*       bb1   = (float*)wp;       wp += 2048 * 4;
    float*       bb2   = (float*)wp;       wp += 2048 * 4;

    // ---- prep: permuted splits, int8 quant, cvts, bias packing ----
    prep_kernel<<<4225, 256, 0, stream>>>(
        state, w1, w2, w3, w11, w21, w12, w22,
        b1, b2, b3, b11, b21, b12, b22,
        Ap, Wp, w1q, wsc, w2b, b123, bb1, bb2);

    // ---- fused currents GEMM + LIF -> spike counts int8 [2048, 4096] ----
    // grid (64,16): bx fast-varying => per-XCD bx-striping (see kernel note)
    fused_cur_lif<<<dim3(64, 16), 512, 0, stream>>>(Ap, Wp, b123, wl, bl, xb);

    // ---- MLP layer 1 (both branches) i8 K=64 MFMA, 512 blocks ----
    mlp1_i8<<<dim3(32, 16), 256, 0, stream>>>(xb, w1q, wsc, bb1, h1);

    // ---- MLP layer 2 (block-diagonal) bf16, 512 blocks ----
    mlp2_bf16<<<dim3(32, 16), 256, 0, stream>>>(
        h1, w2b, bb2, h2, 2048, 1024, 2048, 1024, 2048, 1024);

    // ---- heads (both branches) ----
    head_kernel<<<512, 256, 0, stream>>>(h2, wm, bm, ws, bs, out);
}

// Round 9
// 353.052 us; speedup vs baseline: 1.1315x; 1.0434x over previous
//
#include <hip/hip_runtime.h>
#include <cstddef>
#include <cstdint>

#define THRESH 0.8f
#define DECAY  0.2f

typedef unsigned short ushort_t;
typedef __attribute__((ext_vector_type(8))) short bf16x8;
typedef __attribute__((ext_vector_type(4))) float f32x4;
typedef __attribute__((ext_vector_type(4))) int i32x4;   // also 16 x i8 operand

__device__ __forceinline__ ushort_t f2bf(float f) {
    union { float f; unsigned u; } v; v.f = f;
    unsigned r = v.u + 0x7FFFu + ((v.u >> 16) & 1u);
    return (ushort_t)(r >> 16);
}
__device__ __forceinline__ float bf2f(ushort_t h) {
    union { unsigned u; float f; } v; v.u = ((unsigned)h) << 16;
    return v.f;
}
__device__ __forceinline__ float blo(unsigned u) {
    union { unsigned x; float f; } v; v.x = u << 16; return v.f;
}
__device__ __forceinline__ float bhi(unsigned u) {
    union { unsigned x; float f; } v; v.x = u & 0xFFFF0000u; return v.f;
}

// async global->LDS, 16B per lane; LDS dest = wave-uniform base + lane*16
__device__ __forceinline__ void gload16(const void* g, void* l) {
    __builtin_amdgcn_global_load_lds(
        (const __attribute__((address_space(1))) void*)g,
        (__attribute__((address_space(3))) void*)l,
        16, 0, 0);
}

// compiler-invisible LDS read (keeps waitcnt control out of the compiler)
#define DSREAD(dst, addr, off) \
    asm volatile("ds_read_b128 %0, %1 offset:" #off : "=v"(dst) : "v"(addr))

#define MM(i, j, a, w) \
    acc[i][j] = __builtin_amdgcn_mfma_f32_16x16x32_bf16(a, w, acc[i][j], 0, 0, 0)

// ---------------------------------------------------------------------------
// Fused currents-GEMM + LIF recurrence -- the R5/R8 configuration, verified
// best (122.8 us, FETCH 91 MB, WRITE 32 MB).  UNCHANGED this round.
//
// Measured DO-NOTs (R6/R7 post-mortems):
//  (1) GRID dim3(64,16), bx fast-varying, is load-bearing: xcd = bid%8 =
//      bx%8 stripes A panels per-XCD (L2-resident across all by); the
//      by-per-XCD swizzle thrashed L2 (FETCH 91 -> 324 MB).
//  (2) Operands deliberately NOT dedup'd: A' = [Ah|Ah|Al] (K=1536),
//      W' = [Wh|Wl|Wh].  K=1024 dedup + tile remap re-reads the same bytes
//      16 tiles later -> evicted -> re-fetch (FETCH 91 -> 134 MB, 121 ->
//      214 us).  Three streamed regions beat one re-read region.
// ---------------------------------------------------------------------------
__global__ __launch_bounds__(512, 4) void fused_cur_lif(
    const ushort_t* __restrict__ A, const ushort_t* __restrict__ W,
    const float* __restrict__ b123, const float* __restrict__ wl,
    const float* __restrict__ bl, signed char* __restrict__ xb)
{
    // [buf][ A: 160x32 (5120 us) | B: 192x32 (6144 us) ] = 22.5KB x 3
    __shared__ ushort_t lds[3][11264];

    const int t = threadIdx.x;
    const int bx = blockIdx.x;           // 0..63  (m: 32 batches each)  FAST
    const int by = blockIdx.y;           // 0..15  (n: 64 channels each) SLOW
    const int lane = t & 63;
    const int wv = t >> 6;
    const int wm = (wv >> 2) * 80;       // wave m-offset: 0 / 80
    const int wn = (wv & 3) * 48;        // wave n-offset: 0/48/96/144
    const int fr = lane & 15;
    const int fq = lane >> 4;
    const int swz16 = (fq ^ ((fr >> 1) & 3)) * 16;   // read swizzle, bytes

    // per-buffer ds_read base addresses (bytes); buffer stride 22528
    const unsigned av0 = (unsigned)((wm + fr) * 64 + swz16);
    const unsigned av1 = av0 + 22528;
    const unsigned av2 = av0 + 45056;
    const unsigned bv0 = (unsigned)(10240 + (wn + fr) * 64 + swz16);
    const unsigned bv1 = bv0 + 22528;
    const unsigned bv2 = bv0 + 45056;

    // staging role: waves 0-4 stage A (2 x 16-row groups), 5-7 stage B (4)
    const ushort_t* src0; const ushort_t* src1;
    const ushort_t* src2; const ushort_t* src3;
    int dst0, dst1, dst2, dst3;
    if (wv < 5) {
        const int rl0 = wv * 32 + (lane >> 2);
        const int rl1 = rl0 + 16;
        src0 = A + (size_t)(bx * 160 + rl0) * 1536 + ((lane & 3) ^ ((rl0 >> 1) & 3)) * 8;
        src1 = A + (size_t)(bx * 160 + rl1) * 1536 + ((lane & 3) ^ ((rl1 >> 1) & 3)) * 8;
        src2 = src0; src3 = src1;
        dst0 = rl0 * 32 + (lane & 3) * 8;
        dst1 = rl1 * 32 + (lane & 3) * 8;
        dst2 = dst0; dst3 = dst1;
    } else {
        const int rb = (wv - 5) * 64 + (lane >> 2);
        src0 = W + (size_t)(by * 192 + rb) * 1536 + ((lane & 3) ^ ((rb >> 1) & 3)) * 8;
        src1 = src0 + (size_t)16 * 1536;
        src2 = src0 + (size_t)32 * 1536;
        src3 = src0 + (size_t)48 * 1536;
        dst0 = 5120 + rb * 32 + (lane & 3) * 8;
        dst1 = dst0 + 16 * 32;
        dst2 = dst0 + 32 * 32;
        dst3 = dst0 + 48 * 32;
    }

#define STAGE(tile, sbuf)                                              \
    do {                                                               \
        ushort_t* lb_ = &lds[sbuf][0];                                 \
        if (wv < 5) {                                                  \
            gload16(src0 + (tile) * 32, lb_ + dst0);                   \
            gload16(src1 + (tile) * 32, lb_ + dst1);                   \
        } else {                                                       \
            gload16(src0 + (tile) * 32, lb_ + dst0);                   \
            gload16(src1 + (tile) * 32, lb_ + dst1);                   \
            gload16(src2 + (tile) * 32, lb_ + dst2);                   \
            gload16(src3 + (tile) * 32, lb_ + dst3);                   \
        }                                                              \
    } while (0)

#define COMPUTE(av_, bv_)                                              \
    do {                                                               \
        bf16x8 af0, af1, af2, af3, af4, wf0, wf1, wf2;                 \
        DSREAD(af0, av_, 0);                                           \
        DSREAD(af1, av_, 1024);                                        \
        DSREAD(af2, av_, 2048);                                        \
        DSREAD(af3, av_, 3072);                                        \
        DSREAD(af4, av_, 4096);                                        \
        DSREAD(wf0, bv_, 0);                                           \
        DSREAD(wf1, bv_, 1024);                                        \
        DSREAD(wf2, bv_, 2048);                                        \
        asm volatile("s_waitcnt lgkmcnt(0)" ::: "memory");             \
        __builtin_amdgcn_sched_barrier(0);                             \
        __builtin_amdgcn_s_setprio(1);                                 \
        MM(0, 0, af0, wf0); MM(0, 1, af0, wf1); MM(0, 2, af0, wf2);    \
        MM(1, 0, af1, wf0); MM(1, 1, af1, wf1); MM(1, 2, af1, wf2);    \
        MM(2, 0, af2, wf0); MM(2, 1, af2, wf1); MM(2, 2, af2, wf2);    \
        MM(3, 0, af3, wf0); MM(3, 1, af3, wf1); MM(3, 2, af3, wf2);    \
        MM(4, 0, af4, wf0); MM(4, 1, af4, wf1); MM(4, 2, af4, wf2);    \
        __builtin_amdgcn_s_setprio(0);                                 \
    } while (0)

    f32x4 acc[5][3];
#pragma unroll
    for (int i = 0; i < 5; i++)
#pragma unroll
        for (int j = 0; j < 3; j++) {
            f32x4 z = {0.f, 0.f, 0.f, 0.f};
            acc[i][j] = z;
        }

    // prologue: tiles 0,1 in flight
    STAGE(0, 0);
    STAGE(1, 1);

    // main loop, fully unrolled: tiles 0..45, staging 2..47
#pragma unroll
    for (int tt = 0; tt < 46; ++tt) {
        STAGE(tt + 2, (tt + 2) % 3);
        if (wv < 5) asm volatile("s_waitcnt vmcnt(4)" ::: "memory");
        else        asm volatile("s_waitcnt vmcnt(8)" ::: "memory");
        __builtin_amdgcn_s_barrier();
        __builtin_amdgcn_sched_barrier(0);
        const unsigned av_ = (tt % 3 == 0) ? av0 : (tt % 3 == 1) ? av1 : av2;
        const unsigned bv_ = (tt % 3 == 0) ? bv0 : (tt % 3 == 1) ? bv1 : bv2;
        COMPUTE(av_, bv_);
        __builtin_amdgcn_s_barrier();
        __builtin_amdgcn_sched_barrier(0);
    }
    // tt = 46 (buffer 1): only tile 47's loads still outstanding
    if (wv < 5) asm volatile("s_waitcnt vmcnt(2)" ::: "memory");
    else        asm volatile("s_waitcnt vmcnt(4)" ::: "memory");
    __builtin_amdgcn_s_barrier();
    __builtin_amdgcn_sched_barrier(0);
    COMPUTE(av1, bv1);
    __builtin_amdgcn_s_barrier();
    __builtin_amdgcn_sched_barrier(0);
    // tt = 47 (buffer 2): drain
    asm volatile("s_waitcnt vmcnt(0)" ::: "memory");
    __builtin_amdgcn_s_barrier();
    __builtin_amdgcn_sched_barrier(0);
    COMPUTE(av2, bv2);
#undef STAGE
#undef COMPUTE

    // ---- epilogue: in-register LIF recurrence (replaces recur_kernel) ----
    const int ch = by * 64 + (wv & 3) * 16 + fr;
    const float b1c = b123[ch];
    const float b2c = b123[1024 + ch];
    const float b3c = b123[2048 + ch];
    const float wl0 = wl[0], wl1 = wl[1], wl2 = wl[2], bl0 = bl[0];
    const int bbase = bx * 32 + (wv >> 2) * 16 + fq * 4;
#pragma unroll
    for (int r = 0; r < 4; r++) {
        float m0 = 0.f, m1 = 0.f, m2 = 0.f, m3 = 0.f;
        int s0 = 0, s1 = 0, s2 = 0, s3 = 0;
#pragma unroll
        for (int f = 0; f < 5; f++) {
            const float i1 = acc[f][0][r] + b1c;
            const float i2 = acc[f][1][r] + b2c;
            const float i3 = acc[f][2][r] + b3c;
#pragma unroll
            for (int rep = 0; rep < 3; rep++) {
                const float inner = m0 * wl0 + m1 * wl1 + m2 * wl2 + bl0;
                const float n0 = i1 + ((m0 > THRESH) ? 0.f : DECAY * m0);
                const float n1 = i2 + ((m1 > THRESH) ? 0.f : DECAY * m1);
                const float n2 = i3 + ((m2 > THRESH) ? 0.f : DECAY * m2);
                const float n3 = inner + ((m3 > THRESH) ? 0.f : DECAY * m3);
                m0 = n0; m1 = n1; m2 = n2; m3 = n3;
                s0 += (n0 > THRESH); s1 += (n1 > THRESH);
                s2 += (n2 > THRESH); s3 += (n3 > THRESH);
            }
        }
        uchar4 o;
        o.x = (unsigned char)s0; o.y = (unsigned char)s1;
        o.z = (unsigned char)s2; o.w = (unsigned char)s3;
        *(uchar4*)&xb[(size_t)(bbase + r) * 4096 + ch * 4] = o;
    }
}

// ---------------------------------------------------------------------------
// MLP layer 1, int8 MFMA (16x16x64) -- NOW with the proven R5 pipeline:
// single LDS array (base 0 for asm addressing), 3 buffers x 12 KB = 36 KB
// (2 blocks/CU preserved), prefetch distance 2, uniform 3 loads/thread/tile
// -> steady vmcnt(6), tail 3 -> 0; asm ds_reads + lgkmcnt(0) fence,
// 2 barriers/tile, setprio, fully-unrolled K-loop (64 tiles, offsets fold).
// Math/accumulation order identical to the previous 2-barrier version.
// Buffer layout (bytes): A 64x64 @ [0,4096) | W 128x64 @ [4096,12288).
// ---------------------------------------------------------------------------
__global__ __launch_bounds__(256, 2) void mlp1_i8(
    const signed char* __restrict__ A, const signed char* __restrict__ W,
    const float* __restrict__ wsc, const float* __restrict__ bias,
    ushort_t* __restrict__ C)
{
    __shared__ signed char lds[3][12288];

    const int t = threadIdx.x;
    const int mBase = blockIdx.x * 64;
    const int nBase = blockIdx.y * 128;

    const int lane = t & 63;
    const int wv = t >> 6;               // 0..3
    const int wn = wv * 32;
    const int fr = lane & 15;
    const int fq = lane >> 4;
    const int fsw = (fq ^ ((fr >> 1) & 3)) * 16;     // read swizzle, bytes

    // ds_read bases (bytes); buffer stride 12288
    const unsigned a0 = (unsigned)(fr * 64 + fsw);
    const unsigned a1 = a0 + 12288, a2 = a0 + 24576;
    const unsigned b0 = (unsigned)(4096 + (wn + fr) * 64 + fsw);
    const unsigned b1 = b0 + 12288, b2 = b0 + 24576;

    // staging: thread t covers row r0 chunk (t&3), pre-swizzled source
    const int r0 = t >> 2;                            // 0..63
    const int cc = ((t & 3) ^ ((r0 >> 1) & 3)) * 16;  // src byte-col
    const signed char* srcA  = A + (size_t)(mBase + r0) * 4096 + cc;
    const signed char* srcW0 = W + (size_t)(nBase + r0) * 4096 + cc;
    const signed char* srcW1 = W + (size_t)(nBase + 64 + r0) * 4096 + cc;

#define STAGE1(tile)                                                   \
    do {                                                               \
        signed char* lb_ = &lds[(tile) % 3][0];                        \
        gload16(srcA  + (tile) * 64, lb_ + t * 16);                    \
        gload16(srcW0 + (tile) * 64, lb_ + 4096 + t * 16);             \
        gload16(srcW1 + (tile) * 64, lb_ + 8192 + t * 16);             \
    } while (0)

#define COMPUTE1(av_, bv_)                                             \
    do {                                                               \
        i32x4 af0, af1, af2, af3, wf0, wf1;                            \
        DSREAD(af0, av_, 0);                                           \
        DSREAD(af1, av_, 1024);                                        \
        DSREAD(af2, av_, 2048);                                        \
        DSREAD(af3, av_, 3072);                                        \
        DSREAD(wf0, bv_, 0);                                           \
        DSREAD(wf1, bv_, 1024);                                        \
        asm volatile("s_waitcnt lgkmcnt(0)" ::: "memory");             \
        __builtin_amdgcn_sched_barrier(0);                             \
        __builtin_amdgcn_s_setprio(1);                                 \
        acc[0][0] = __builtin_amdgcn_mfma_i32_16x16x64_i8(af0, wf0, acc[0][0], 0, 0, 0); \
        acc[0][1] = __builtin_amdgcn_mfma_i32_16x16x64_i8(af0, wf1, acc[0][1], 0, 0, 0); \
        acc[1][0] = __builtin_amdgcn_mfma_i32_16x16x64_i8(af1, wf0, acc[1][0], 0, 0, 0); \
        acc[1][1] = __builtin_amdgcn_mfma_i32_16x16x64_i8(af1, wf1, acc[1][1], 0, 0, 0); \
        acc[2][0] = __builtin_amdgcn_mfma_i32_16x16x64_i8(af2, wf0, acc[2][0], 0, 0, 0); \
        acc[2][1] = __builtin_amdgcn_mfma_i32_16x16x64_i8(af2, wf1, acc[2][1], 0, 0, 0); \
        acc[3][0] = __builtin_amdgcn_mfma_i32_16x16x64_i8(af3, wf0, acc[3][0], 0, 0, 0); \
        acc[3][1] = __builtin_amdgcn_mfma_i32_16x16x64_i8(af3, wf1, acc[3][1], 0, 0, 0); \
        __builtin_amdgcn_s_setprio(0);                                 \
    } while (0)

    i32x4 acc[4][2];
#pragma unroll
    for (int i = 0; i < 4; i++)
#pragma unroll
        for (int j = 0; j < 2; j++) {
            i32x4 z = {0, 0, 0, 0};
            acc[i][j] = z;
        }

    // prologue: tiles 0,1 in flight (3 loads each -> 6 outstanding)
    STAGE1(0);
    STAGE1(1);

    // main loop: tiles 0..61, staging 2..63; steady vmcnt(6) = 2 tiles ahead
#pragma unroll
    for (int tt = 0; tt < 62; ++tt) {
        STAGE1(tt + 2);
        asm volatile("s_waitcnt vmcnt(6)" ::: "memory");
        __builtin_amdgcn_s_barrier();
        __builtin_amdgcn_sched_barrier(0);
        const unsigned av_ = (tt % 3 == 0) ? a0 : (tt % 3 == 1) ? a1 : a2;
        const unsigned bv_ = (tt % 3 == 0) ? b0 : (tt % 3 == 1) ? b1 : b2;
        COMPUTE1(av_, bv_);
        __builtin_amdgcn_s_barrier();
        __builtin_amdgcn_sched_barrier(0);
    }
    // tt = 62 (buffer 2): only tile 63's loads outstanding after wait
    asm volatile("s_waitcnt vmcnt(3)" ::: "memory");
    __builtin_amdgcn_s_barrier();
    __builtin_amdgcn_sched_barrier(0);
    COMPUTE1(a2, b2);
    __builtin_amdgcn_s_barrier();
    __builtin_amdgcn_sched_barrier(0);
    // tt = 63 (buffer 0): drain
    asm volatile("s_waitcnt vmcnt(0)" ::: "memory");
    __builtin_amdgcn_s_barrier();
    __builtin_amdgcn_sched_barrier(0);
    COMPUTE1(a0, b0);
#undef STAGE1
#undef COMPUTE1

#pragma unroll
    for (int j = 0; j < 2; j++) {
        const int col = nBase + wn + j * 16 + fr;
        const float sc = wsc[col];
        const float bv = bias[col];
#pragma unroll
        for (int i = 0; i < 4; i++)
#pragma unroll
            for (int r = 0; r < 4; r++) {
                const int row = mBase + i * 16 + fq * 4 + r;
                const float v = (float)acc[i][j][r] * sc + bv;
                C[(size_t)row * 2048 + col] = f2bf(fmaxf(v, 0.f));
            }
    }
}

// ---------------------------------------------------------------------------
// MLP layer 2: bf16, 64x128 tile, block-diagonal -- same R5-pipeline port.
// Buffer layout (bytes): A 64x32us @ [0,4096) | W 128x32us @ [4096,12288).
// 32 K-tiles; steady vmcnt(6), tail 3 -> 0.
// ---------------------------------------------------------------------------
__global__ __launch_bounds__(256, 2) void mlp2_bf16(
    const ushort_t* __restrict__ A, const ushort_t* __restrict__ W,
    const float* __restrict__ bias, ushort_t* __restrict__ C,
    int N, int K, int lda, int ldw, int ldc, int aHalfOff)
{
    __shared__ ushort_t lds[3][6144];

    const int t = threadIdx.x;
    const int mBase = blockIdx.x * 64;
    const int nBase = blockIdx.y * 128;
    const int aOff = (2 * nBase >= N) ? aHalfOff : 0;

    const int lane = t & 63;
    const int wv = t >> 6;
    const int wn = wv * 32;
    const int fr = lane & 15;
    const int fq = lane >> 4;
    const int fsw = (fq ^ ((fr >> 1) & 3)) * 16;     // read swizzle, BYTES

    // ds_read bases (bytes); buffer stride 12288
    const unsigned a0 = (unsigned)(fr * 64 + fsw);
    const unsigned a1 = a0 + 12288, a2 = a0 + 24576;
    const unsigned b0 = (unsigned)(4096 + (wn + fr) * 64 + fsw);
    const unsigned b1 = b0 + 12288, b2 = b0 + 24576;

    const int r0 = t >> 2;                            // 0..63
    const int cc = ((t & 3) ^ ((r0 >> 1) & 3)) * 8;   // src col, ushorts
    const ushort_t* srcA  = A + (size_t)(mBase + r0) * lda + aOff + cc;
    const ushort_t* srcW0 = W + (size_t)(nBase + r0) * ldw + cc;
    const ushort_t* srcW1 = W + (size_t)(nBase + 64 + r0) * ldw + cc;

#define STAGE2(tile)                                                   \
    do {                                                               \
        char* lb_ = (char*)&lds[(tile) % 3][0];                        \
        gload16(srcA  + (tile) * 32, lb_ + t * 16);                    \
        gload16(srcW0 + (tile) * 32, lb_ + 4096 + t * 16);             \
        gload16(srcW1 + (tile) * 32, lb_ + 8192 + t * 16);             \
    } while (0)

#define COMPUTE2(av_, bv_)                                             \
    do {                                                               \
        bf16x8 af0, af1, af2, af3, wf0, wf1;                           \
        DSREAD(af0, av_, 0);                                           \
        DSREAD(af1, av_, 1024);                                        \
        DSREAD(af2, av_, 2048);                                        \
        DSREAD(af3, av_, 3072);                                        \
        DSREAD(wf0, bv_, 0);                                           \
        DSREAD(wf1, bv_, 1024);                                        \
        asm volatile("s_waitcnt lgkmcnt(0)" ::: "memory");             \
        __builtin_amdgcn_sched_barrier(0);                             \
        __builtin_amdgcn_s_setprio(1);                                 \
        MM(0, 0, af0, wf0); MM(0, 1, af0, wf1);                        \
        MM(1, 0, af1, wf0); MM(1, 1, af1, wf1);                        \
        MM(2, 0, af2, wf0); MM(2, 1, af2, wf1);                        \
        MM(3, 0, af3, wf0); MM(3, 1, af3, wf1);                        \
        __builtin_amdgcn_s_setprio(0);                                 \
    } while (0)

    f32x4 acc[4][2];
#pragma unroll
    for (int i = 0; i < 4; i++)
#pragma unroll
        for (int j = 0; j < 2; j++) {
            f32x4 z = {0.f, 0.f, 0.f, 0.f};
            acc[i][j] = z;
        }

    // prologue
    STAGE2(0);
    STAGE2(1);

    // main loop: tiles 0..29, staging 2..31
#pragma unroll
    for (int tt = 0; tt < 30; ++tt) {
        STAGE2(tt + 2);
        asm volatile("s_waitcnt vmcnt(6)" ::: "memory");
        __builtin_amdgcn_s_barrier();
        __builtin_amdgcn_sched_barrier(0);
        const unsigned av_ = (tt % 3 == 0) ? a0 : (tt % 3 == 1) ? a1 : a2;
        const unsigned bv_ = (tt % 3 == 0) ? b0 : (tt % 3 == 1) ? b1 : b2;
        COMPUTE2(av_, bv_);
        __builtin_amdgcn_s_barrier();
        __builtin_amdgcn_sched_barrier(0);
    }
    // tt = 30 (buffer 0)
    asm volatile("s_waitcnt vmcnt(3)" ::: "memory");
    __builtin_amdgcn_s_barrier();
    __builtin_amdgcn_sched_barrier(0);
    COMPUTE2(a0, b0);
    __builtin_amdgcn_s_barrier();
    __builtin_amdgcn_sched_barrier(0);
    // tt = 31 (buffer 1): drain
    asm volatile("s_waitcnt vmcnt(0)" ::: "memory");
    __builtin_amdgcn_s_barrier();
    __builtin_amdgcn_sched_barrier(0);
    COMPUTE2(a1, b1);
#undef STAGE2
#undef COMPUTE2

#pragma unroll
    for (int j = 0; j < 2; j++) {
        const int col = nBase + wn + j * 16 + fr;
        const float bv = bias[col];
#pragma unroll
        for (int i = 0; i < 4; i++)
#pragma unroll
            for (int r = 0; r < 4; r++) {
                const int row = mBase + i * 16 + fq * 4 + r;
                C[(size_t)row * ldc + col] = f2bf(fmaxf(acc[i][j][r] + bv, 0.f));
            }
    }
}

// ---------------------------------------------------------------------------
// Consolidated prep (unchanged from R8):
//  - state -> A'' (row-permuted, K-concat [hi|hi|lo], 1536-wide -- NOT
//    dedup'd, see fused kernel DO-NOT (2))
//  - w1/w2/w3 -> W'' (row-permuted, K-concat [hi|lo|hi])
//  - w11|w21 -> int8 rows with per-row scale (shuffle-based reduction)
//  - w12/w22 -> bf16; bias packing
// ---------------------------------------------------------------------------
__device__ __forceinline__ void split_state_perm(const float4* src, ushort4* dst,
                                                 int base, int t) {
#pragma unroll
    for (int p = 0; p < 4; p++) {
        const int i = base * 1024 + p * 256 + t;
        const float4 v = src[i];
        ushort4 h, l;
        h.x = f2bf(v.x); l.x = f2bf(v.x - bf2f(h.x));
        h.y = f2bf(v.y); l.y = f2bf(v.y - bf2f(h.y));
        h.z = f2bf(v.z); l.z = f2bf(v.z - bf2f(h.z));
        h.w = f2bf(v.w); l.w = f2bf(v.w - bf2f(h.w));
        const int s = i >> 7, c4 = i & 127;      // source row (b*5+f), f4-col
        const int b = s / 5, f = s - b * 5;
        const int m = ((b >> 5) * 160) + (((b >> 4) & 1) * 80) + (f << 4) + (b & 15);
        ushort4* row = dst + (size_t)m * 384;    // 1536 ushorts = 384 ushort4
        row[c4] = h; row[128 + c4] = h; row[256 + c4] = l;   // [hi|hi|lo]
    }
}
__device__ __forceinline__ void split_w_perm(const float4* src, ushort4* dst,
                                             int base, int t, int j) {
#pragma unroll
    for (int p = 0; p < 4; p++) {
        const int i = base * 1024 + p * 256 + t;
        const float4 v = src[i];
        ushort4 h, l;
        h.x = f2bf(v.x); l.x = f2bf(v.x - bf2f(h.x));
        h.y = f2bf(v.y); l.y = f2bf(v.y - bf2f(h.y));
        h.z = f2bf(v.z); l.z = f2bf(v.z - bf2f(h.z));
        h.w = f2bf(v.w); l.w = f2bf(v.w - bf2f(h.w));
        const int c = i >> 7, c4 = i & 127;      // source row (channel), f4-col
        const int n = ((c >> 6) * 192) + (((c >> 4) & 3) * 48) + (j << 4) + (c & 15);
        ushort4* row = dst + (size_t)n * 384;
        row[c4] = h; row[128 + c4] = l; row[256 + c4] = h;   // [hi|lo|hi]
    }
}
__device__ __forceinline__ void do_cvt4(const float4* src, ushort4* dst,
                                        int base, int t) {
#pragma unroll
    for (int p = 0; p < 4; p++) {
        const int i = base * 1024 + p * 256 + t;
        const float4 v = src[i];
        ushort4 h;
        h.x = f2bf(v.x); h.y = f2bf(v.y); h.z = f2bf(v.z); h.w = f2bf(v.w);
        dst[i] = h;
    }
}
__device__ __forceinline__ int q8(float x, float inv) {
    int q = (int)rintf(x * inv);
    q = q > 127 ? 127 : (q < -127 ? -127 : q);
    return q & 0xff;
}

__global__ __launch_bounds__(256) void prep_kernel(
    const float* __restrict__ state,
    const float* __restrict__ w1, const float* __restrict__ w2,
    const float* __restrict__ w3,
    const float* __restrict__ w11, const float* __restrict__ w21,
    const float* __restrict__ w12, const float* __restrict__ w22,
    const float* __restrict__ b1, const float* __restrict__ b2,
    const float* __restrict__ b3, const float* __restrict__ b11,
    const float* __restrict__ b21, const float* __restrict__ b12,
    const float* __restrict__ b22,
    ushort_t* __restrict__ Ap, ushort_t* __restrict__ Wp,
    signed char* __restrict__ w1q, float* __restrict__ wsc,
    ushort_t* __restrict__ w2b,
    float* __restrict__ b123, float* __restrict__ bb1, float* __restrict__ bb2)
{
    const int bid = blockIdx.x;
    const int t = threadIdx.x;
    if (bid < 1280) {
        split_state_perm((const float4*)state, (ushort4*)Ap, bid, t);
    } else if (bid < 1408) {
        split_w_perm((const float4*)w1, (ushort4*)Wp, bid - 1280, t, 0);
    } else if (bid < 1536) {
        split_w_perm((const float4*)w2, (ushort4*)Wp, bid - 1408, t, 1);
    } else if (bid < 1664) {
        split_w_perm((const float4*)w3, (ushort4*)Wp, bid - 1536, t, 2);
    } else if (bid < 3712) {
        // one block per output row of [w11 ; w21] -> int8 + per-row scale
        const int r = bid - 1664;
        const float* src = (r < 1024) ? (w11 + (size_t)r * 4096)
                                      : (w21 + (size_t)(r - 1024) * 4096);
        __shared__ float red4[4];
        float4 v[4];
        float lmax = 0.f;
#pragma unroll
        for (int p = 0; p < 4; p++) {
            v[p] = ((const float4*)src)[t * 4 + p];
            lmax = fmaxf(lmax, fmaxf(fmaxf(fabsf(v[p].x), fabsf(v[p].y)),
                                     fmaxf(fabsf(v[p].z), fabsf(v[p].w))));
        }
#pragma unroll
        for (int d = 1; d < 64; d <<= 1)
            lmax = fmaxf(lmax, __shfl_xor(lmax, d, 64));
        if ((t & 63) == 0) red4[t >> 6] = lmax;
        __syncthreads();
        const float gmax = fmaxf(fmaxf(fmaxf(red4[0], red4[1]),
                                       fmaxf(red4[2], red4[3])), 1e-30f);
        const float inv = 127.0f / gmax;
        int4 o;
        o.x = q8(v[0].x, inv) | (q8(v[0].y, inv) << 8) | (q8(v[0].z, inv) << 16) | (q8(v[0].w, inv) << 24);
        o.y = q8(v[1].x, inv) | (q8(v[1].y, inv) << 8) | (q8(v[1].z, inv) << 16) | (q8(v[1].w, inv) << 24);
        o.z = q8(v[2].x, inv) | (q8(v[2].y, inv) << 8) | (q8(v[2].z, inv) << 16) | (q8(v[2].w, inv) << 24);
        o.w = q8(v[3].x, inv) | (q8(v[3].y, inv) << 8) | (q8(v[3].z, inv) << 16) | (q8(v[3].w, inv) << 24);
        ((int4*)(w1q + (size_t)r * 4096))[t] = o;
        if (t == 0) wsc[r] = gmax / (127.0f * 15.0f);
    } else if (bid < 3968) {
        do_cvt4((const float4*)w12, (ushort4*)w2b, bid - 3712, t);
    } else if (bid < 4224) {
        do_cvt4((const float4*)w22, (ushort4*)(w2b + 1048576), bid - 3968, t);
    } else {
#pragma unroll
        for (int p = 0; p < 4; p++) {
            const int i = p * 256 + t;
            b123[i] = b1[i]; b123[1024 + i] = b2[i]; b123[2048 + i] = b3[i];
            bb1[i] = b11[i]; bb1[1024 + i] = b21[i];
            bb2[i] = b12[i]; bb2[1024 + i] = b22[i];
        }
    }
}

// ---------------------------------------------------------------------------
// Heads (both branches): out[b][n] = (clip?)(h2[b][off+k] . w[n][k] + bias[n])
// ---------------------------------------------------------------------------
__global__ __launch_bounds__(256) void head_kernel(
    const ushort_t* __restrict__ h, const float* __restrict__ wm,
    const float* __restrict__ bm, const float* __restrict__ ws,
    const float* __restrict__ bs, float* __restrict__ out)
{
    const int t = threadIdx.x;
    const int branch = blockIdx.x >> 8;
    const int n = t & 31;
    const int b = (blockIdx.x & 255) * 8 + (t >> 5);
    const ushort_t* hr = h + (size_t)b * 2048 + branch * 1024;
    const float* wr = (branch ? ws : wm) + (size_t)n * 1024;
    float s = 0.f;
#pragma unroll 4
    for (int k = 0; k < 1024; k += 8) {
        const uint4 hv = *(const uint4*)&hr[k];
        const float4 w0 = *(const float4*)&wr[k];
        const float4 w1 = *(const float4*)&wr[k + 4];
        s += blo(hv.x) * w0.x + bhi(hv.x) * w0.y
           + blo(hv.y) * w0.z + bhi(hv.y) * w0.w
           + blo(hv.z) * w1.x + bhi(hv.z) * w1.y
           + blo(hv.w) * w1.z + bhi(hv.w) * w1.w;
    }
    s += (branch ? bs : bm)[n];
    if (branch) s = fminf(fmaxf(s, -20.f), 2.f);
    out[(size_t)branch * 65536 + (size_t)b * 32 + n] = s;
}

// ---------------------------------------------------------------------------
extern "C" void kernel_launch(void* const* d_in, const int* in_sizes, int n_in,
                              void* d_out, int out_size, void* d_ws, size_t ws_size,
                              hipStream_t stream)
{
    const float* state = (const float*)d_in[0];
    const float* w1  = (const float*)d_in[1];  const float* b1  = (const float*)d_in[2];
    const float* w2  = (const float*)d_in[3];  const float* b2  = (const float*)d_in[4];
    const float* w3  = (const float*)d_in[5];  const float* b3  = (const float*)d_in[6];
    const float* wl  = (const float*)d_in[7];  const float* bl  = (const float*)d_in[8];
    const float* w11 = (const float*)d_in[9];  const float* b11 = (const float*)d_in[10];
    const float* w12 = (const float*)d_in[11]; const float* b12 = (const float*)d_in[12];
    const float* w21 = (const float*)d_in[13]; const float* b21 = (const float*)d_in[14];
    const float* w22 = (const float*)d_in[15]; const float* b22 = (const float*)d_in[16];
    const float* wm  = (const float*)d_in[17]; const float* bm  = (const float*)d_in[18];
    const float* ws  = (const float*)d_in[19]; const float* bs  = (const float*)d_in[20];
    float* out = (float*)d_out;

    // ---- workspace layout ----
    char* wp = (char*)d_ws;
    ushort_t*    Ap    = (ushort_t*)wp;    wp += (size_t)10240 * 1536 * 2;   // 31.5MB
    ushort_t*    Wp    = (ushort_t*)wp;    wp += (size_t)3072 * 1536 * 2;    // 9.4MB
    signed char* xb    = (signed char*)wp; wp += (size_t)2048 * 4096;        // int8 counts
    signed char* w1q   = (signed char*)wp; wp += (size_t)2048 * 4096;        // int8 [w11;w21]
    ushort_t*    w2b   = (ushort_t*)wp;    wp += (size_t)2048 * 1024 * 2;
    ushort_t*    h1    = (ushort_t*)wp;    wp += (size_t)2048 * 2048 * 2;
    ushort_t*    h2    = (ushort_t*)wp;    wp += (size_t)2048 * 2048 * 2;
    float*       wsc   = (float*)wp;       wp += 2048 * 4;
    float*       b123  = (float*)wp;       wp += 3072 * 4;
    float*       bb1   = (float*)wp;       wp += 2048 * 4;
    float*       bb2   = (float*)wp;       wp += 2048 * 4;

    // ---- prep: permuted splits, int8 quant, cvts, bias packing ----
    prep_kernel<<<4225, 256, 0, stream>>>(
        state, w1, w2, w3, w11, w21, w12, w22,
        b1, b2, b3, b11, b21, b12, b22,
        Ap, Wp, w1q, wsc, w2b, b123, bb1, bb2);

    // ---- fused currents GEMM + LIF -> spike counts int8 [2048, 4096] ----
    // grid (64,16): bx fast-varying => per-XCD bx-striping (see kernel note)
    fused_cur_lif<<<dim3(64, 16), 512, 0, stream>>>(Ap, Wp, b123, wl, bl, xb);

    // ---- MLP layer 1 (both branches) i8 K=64 MFMA, 512 blocks ----
    mlp1_i8<<<dim3(32, 16), 256, 0, stream>>>(xb, w1q, wsc, bb1, h1);

    // ---- MLP layer 2 (block-diagonal) bf16, 512 blocks ----
    mlp2_bf16<<<dim3(32, 16), 256, 0, stream>>>(
        h1, w2b, bb2, h2, 2048, 1024, 2048, 1024, 2048, 1024);

    // ---- heads (both branches) ----
    head_kernel<<<512, 256, 0, stream>>>(h2, wm, bm, ws, bs, out);
}